// Round 17
// baseline (128.784 us; speedup 1.0000x reference)
//
#include <hip/hip_runtime.h>

#define N_PIX 4096
#define CCH 256
#define DV 128

typedef __attribute__((ext_vector_type(8))) short bf16x8;
typedef __attribute__((ext_vector_type(4))) float f32x4;
typedef __attribute__((ext_vector_type(8))) short short8;

__device__ __forceinline__ short f2bf(float f) {
    unsigned u = __builtin_bit_cast(unsigned, f);
    u += 0x7fffu + ((u >> 16) & 1u);
    return (short)(u >> 16);
}

__device__ __forceinline__ float4 bf4_load(const short* p) {
    short4 s = *(const short4*)p;
    float4 f;
    f.x = __builtin_bit_cast(float, (unsigned)((unsigned short)s.x) << 16);
    f.y = __builtin_bit_cast(float, (unsigned)((unsigned short)s.y) << 16);
    f.z = __builtin_bit_cast(float, (unsigned)((unsigned short)s.z) << 16);
    f.w = __builtin_bit_cast(float, (unsigned)((unsigned short)s.w) << 16);
    return f;
}

// ---------------------------------------------------------------------------
// K1: fused 1x1 convs as ONE bf16 MFMA GEMM (r11 exact).
// ---------------------------------------------------------------------------
__global__ __launch_bounds__(512) void qkv_kernel(
    const float* __restrict__ x1, const float* __restrict__ x2,
    const short* __restrict__ wqkv,
    const float* __restrict__ bq, const float* __restrict__ bk,
    const float* __restrict__ bv,
    short* __restrict__ qb, short* __restrict__ kb, short* __restrict__ vb)
{
    __shared__ short xT[64][68];   // [px][c-chunk], pitch 68 shorts

    const int tid = threadIdx.x;
    const int lane = tid & 63;
    const int w = tid >> 6;
    const int g = lane >> 4, l15 = lane & 15;
    const int n0 = blockIdx.x * 64;
    const int ib = blockIdx.y;
    const int i = ib >> 1, b = ib & 1;
    const float* x = (i == 0 ? x1 : x2) + (size_t)b * CCH * N_PIX;

    const int px2 = tid & 31, c4 = tid >> 5;
    const int rhalf = (w >> 2) * 80;

    f32x4 acc[5];
    #pragma unroll
    for (int jl = 0; jl < 5; ++jl) {
        int rbase = rhalf + jl * 16;
        float bias;
        if (rbase == 0)       bias = bq[l15];
        else if (rbase == 16) bias = bk[l15];
        else                  bias = bv[rbase - 32 + l15];
        acc[jl] = (f32x4){bias, bias, bias, bias};
    }

    float2 xr[4];
    {
        #pragma unroll
        for (int jj = 0; jj < 4; ++jj)
            xr[jj] = *(const float2*)&x[(size_t)(c4 * 4 + jj) * N_PIX + n0 + px2 * 2];
    }

    for (int ci = 0; ci < 4; ++ci) {   // 4 chunks x 64 c = K 256
        __syncthreads();
        {
            short4 w0, w1;
            w0.x = f2bf(xr[0].x); w0.y = f2bf(xr[1].x); w0.z = f2bf(xr[2].x); w0.w = f2bf(xr[3].x);
            w1.x = f2bf(xr[0].y); w1.y = f2bf(xr[1].y); w1.z = f2bf(xr[2].y); w1.w = f2bf(xr[3].y);
            *(short4*)&xT[px2 * 2 + 0][c4 * 4] = w0;
            *(short4*)&xT[px2 * 2 + 1][c4 * 4] = w1;
        }
        __syncthreads();
        if (ci < 3) {
            #pragma unroll
            for (int jj = 0; jj < 4; ++jj)
                xr[jj] = *(const float2*)
                    &x[(size_t)((ci + 1) * 64 + c4 * 4 + jj) * N_PIX + n0 + px2 * 2];
        }
        bf16x8 a0 = *(const bf16x8*)&xT[(w & 3) * 16 + l15][g * 8];
        bf16x8 a1 = *(const bf16x8*)&xT[(w & 3) * 16 + l15][32 + g * 8];
        #pragma unroll
        for (int jl = 0; jl < 5; ++jl) {
            int rbase = rhalf + jl * 16;
            const short* wrow = wqkv + (size_t)(rbase + l15) * CCH + ci * 64;
            bf16x8 b0 = *(const bf16x8*)&wrow[g * 8];
            bf16x8 b1 = *(const bf16x8*)&wrow[32 + g * 8];
            acc[jl] = __builtin_amdgcn_mfma_f32_16x16x32_bf16(a0, b0, acc[jl], 0, 0, 0);
            acc[jl] = __builtin_amdgcn_mfma_f32_16x16x32_bf16(a1, b1, acc[jl], 0, 0, 0);
        }
    }

    const int px_base = n0 + (w & 3) * 16 + g * 4;
    #pragma unroll
    for (int jl = 0; jl < 5; ++jl) {
        int rbase = rhalf + jl * 16;
        if (rbase == 0) {
            #pragma unroll
            for (int rr = 0; rr < 4; ++rr)
                qb[((size_t)ib * N_PIX + px_base + rr) * 16 + l15] = f2bf(acc[jl][rr]);
        } else if (rbase == 16) {
            #pragma unroll
            for (int rr = 0; rr < 4; ++rr)
                kb[((size_t)ib * N_PIX + px_base + rr) * 16 + l15] = f2bf(acc[jl][rr]);
        } else {
            int c = rbase - 32 + l15;
            short4 s;
            s.x = f2bf(acc[jl][0]); s.y = f2bf(acc[jl][1]);
            s.z = f2bf(acc[jl][2]); s.w = f2bf(acc[jl][3]);
            *(short4*)&vb[((size_t)ib * DV + c) * N_PIX + px_base] = s;
        }
    }
}

// ---------------------------------------------------------------------------
// K2: MFMA flash attention — r11 dataflow (pitch 72, K staged by wave 3,
// V dbuf in regs) with ONE barrier per chunk: k_lds AND p_lds double-
// buffered so the read-drain barrier is unnecessary. Region between
// barriers = [PV(t-1) | commit K(t+1)->k[!h] | issue K(t+2),V(t+1) | QK(t)].
// Hazards: each buffer's prior reader is one barrier away (audited).
// grid 768: pb=bid&3, mh=(bid>>2)%3, nt=bid/12. 3 blocks/CU, 24.6KB LDS.
// ---------------------------------------------------------------------------
__global__ __launch_bounds__(256, 4) void attn_kernel(
    const short* __restrict__ qg, const short* __restrict__ kg,
    const short* __restrict__ vg,
    float* __restrict__ out1, float* __restrict__ out2,
    short* __restrict__ featp, float* __restrict__ lpart)
{
    __shared__ short k_lds[2][64 * 24];   // dbuf [m][d], pitch 24 shorts
    __shared__ short p_lds[2][64 * 72];   // dbuf [n][m], pitch 72 shorts

    const int tid = threadIdx.x;
    const int lane = tid & 63;
    const int w = tid >> 6;
    const int gk = lane >> 4;
    const int l15 = lane & 15;

    const int B_ = blockIdx.x;
    const int pb = B_ & 3;
    const int mh = (B_ >> 2) % 3;
    const int nt = B_ / 12;
    const int n0 = nt * 64;
    const int br = pb >> 1, b = pb & 1;
    const int tstart = mh * 22;
    const int tend = (mh == 2) ? 64 : tstart + 22;   // 22/22/20, all even

    const short* qp = qg + (size_t)pb * N_PIX * 16;
    const short* kp = kg + (size_t)((br ^ 1) * 2 + b) * N_PIX * 16;
    const short* vp = vg + (size_t)pb * DV * N_PIX;

    bf16x8 aq = {};
    if (lane < 32)
        aq = *(const bf16x8*)&qp[(size_t)(n0 + w * 16 + l15) * 16 + gk * 8];

    f32x4 acc[2][4];
    #pragma unroll
    for (int cc = 0; cc < 2; ++cc)
        #pragma unroll
        for (int nb = 0; nb < 4; ++nb) acc[cc][nb] = (f32x4){0.f, 0.f, 0.f, 0.f};
    float lsum[4] = {0.f, 0.f, 0.f, 0.f};

    const short* vbase = vp + (size_t)(w * 32 + l15) * N_PIX + gk * 8;
    const int krow = tid - 192;

    int4 vbuf0[4], vbuf1[4];
    int4 kr0 = {}, kr1 = {};

    {   // prologue: V(tstart)->vbuf0; K(tstart)->k_lds[0]; K(tstart+1)->kr regs
        #pragma unroll
        for (int cc = 0; cc < 2; ++cc)
            #pragma unroll
            for (int m2 = 0; m2 < 2; ++m2)
                vbuf0[cc * 2 + m2] = *(const int4*)
                    &vbase[(size_t)cc * 16 * N_PIX + tstart * 64 + m2 * 32];
        if (tid >= 192) {
            int4 t0a = *(const int4*)&kp[(size_t)(tstart * 64 + krow) * 16];
            int4 t0b = *(const int4*)&kp[(size_t)(tstart * 64 + krow) * 16 + 8];
            *(int4*)&k_lds[0][krow * 24] = t0a;
            *(int4*)&k_lds[0][krow * 24 + 8] = t0b;
            if (tstart + 1 < tend) {
                kr0 = *(const int4*)&kp[(size_t)((tstart + 1) * 64 + krow) * 16];
                kr1 = *(const int4*)&kp[(size_t)((tstart + 1) * 64 + krow) * 16 + 8];
            }
        }
        __syncthreads();
    }

    for (int t0 = tstart; t0 < tend; t0 += 2) {
        #pragma unroll
        for (int half = 0; half < 2; ++half) {
            const int t = t0 + half;
            int4* vcur = half ? vbuf1 : vbuf0;
            int4* vnxt = half ? vbuf0 : vbuf1;
            // commit K(t+1) (already in regs) into the other k buffer; its
            // previous reader QK(t-1) finished before the last barrier.
            if (t + 1 < tend && tid >= 192) {
                *(int4*)&k_lds[half ^ 1][krow * 24] = kr0;
                *(int4*)&k_lds[half ^ 1][krow * 24 + 8] = kr1;
            }
            // issue K(t+2) and V(t+1); latency hides under QK + barrier + PV
            if (t + 2 < tend && tid >= 192) {
                kr0 = *(const int4*)&kp[(size_t)((t + 2) * 64 + krow) * 16];
                kr1 = *(const int4*)&kp[(size_t)((t + 2) * 64 + krow) * 16 + 8];
            }
            if (t + 1 < tend) {
                #pragma unroll
                for (int cc = 0; cc < 2; ++cc)
                    #pragma unroll
                    for (int m2 = 0; m2 < 2; ++m2)
                        vnxt[cc * 2 + m2] = *(const int4*)
                            &vbase[(size_t)cc * 16 * N_PIX + (t + 1) * 64 + m2 * 32];
            }
            // QK(t): k_lds[half] -> exp -> p_lds[half]
            #pragma unroll
            for (int h = 0; h < 4; ++h) {
                bf16x8 bk_ = {};
                if (lane < 32)
                    bk_ = *(const bf16x8*)&k_lds[half][(h * 16 + l15) * 24 + gk * 8];
                f32x4 s = __builtin_amdgcn_mfma_f32_16x16x32_bf16(
                    aq, bk_, (f32x4){0.f, 0.f, 0.f, 0.f}, 0, 0, 0);
                #pragma unroll
                for (int rr = 0; rr < 4; ++rr) {
                    float e = __expf(s[rr] * 0.25f);
                    lsum[rr] += e;
                    unsigned u = __builtin_bit_cast(unsigned, e);
                    p_lds[half][(w * 16 + gk * 4 + rr) * 72 + h * 16 + l15] = (short)(u >> 16);
                }
            }
            __syncthreads();   // the ONLY barrier per chunk
            // PV(t): p_lds[half] x V(regs)
            __builtin_amdgcn_s_setprio(1);
            #pragma unroll
            for (int m2 = 0; m2 < 2; ++m2) {
                #pragma unroll
                for (int nb = 0; nb < 4; ++nb) {
                    bf16x8 bp = *(const bf16x8*)
                        &p_lds[half][(nb * 16 + l15) * 72 + m2 * 32 + gk * 8];
                    #pragma unroll
                    for (int cc = 0; cc < 2; ++cc) {
                        bf16x8 av = __builtin_bit_cast(bf16x8, vcur[cc * 2 + m2]);
                        acc[cc][nb] = __builtin_amdgcn_mfma_f32_16x16x32_bf16(
                            av, bp, acc[cc][nb], 0, 0, 0);
                    }
                }
            }
            __builtin_amdgcn_s_setprio(0);
            // no trailing barrier: next chunk uses the other buffers
        }
    }

    #pragma unroll
    for (int rr = 0; rr < 4; ++rr) {
        float v = lsum[rr];
        v += __shfl_xor(v, 1); v += __shfl_xor(v, 2);
        v += __shfl_xor(v, 4); v += __shfl_xor(v, 8);
        lsum[rr] = v;
    }
    if (l15 == 0) {
        #pragma unroll
        for (int rr = 0; rr < 4; ++rr)
            lpart[(size_t)(pb * 3 + mh) * N_PIX + n0 + w * 16 + gk * 4 + rr] = lsum[rr];
    }

    if (mh == 0) {   // f32 partial at final location (c<128 of out1/out2)
        float* Od = (br ? out2 : out1) + (size_t)b * CCH * N_PIX;
        #pragma unroll
        for (int cc = 0; cc < 2; ++cc)
            #pragma unroll
            for (int nb = 0; nb < 4; ++nb)
                #pragma unroll
                for (int rr = 0; rr < 4; ++rr) {
                    int c = w * 32 + cc * 16 + gk * 4 + rr;
                    Od[(size_t)c * N_PIX + n0 + nb * 16 + l15] = acc[cc][nb][rr];
                }
    } else {
        // bf16 tiled slot via LDS repack (uses p_lds[0] region, [c][66])
        __syncthreads();
        short* pf = &p_lds[0][0];
        short* Ps = featp + (size_t)(pb * 2 + (mh - 1)) * (64 * 128 * 64)
                          + (size_t)nt * (128 * 64);
        #pragma unroll
        for (int chalf = 0; chalf < 2; ++chalf) {
            if ((w >> 1) == chalf) {   // waves 0,1 -> c 0..63; waves 2,3 -> 64..127
                int crel_base = (w & 1) * 32;
                #pragma unroll
                for (int cc = 0; cc < 2; ++cc)
                    #pragma unroll
                    for (int nb = 0; nb < 4; ++nb)
                        #pragma unroll
                        for (int rr = 0; rr < 4; ++rr) {
                            int crel = crel_base + cc * 16 + gk * 4 + rr;
                            pf[crel * 66 + nb * 16 + l15] = f2bf(acc[cc][nb][rr]);
                        }
            }
            __syncthreads();
            for (int idx = tid; idx < 512; idx += 256) {
                int cr = idx >> 3, seg = idx & 7;
                int4 v = *(const int4*)&pf[cr * 66 + seg * 8];
                *(int4*)&Ps[(size_t)(chalf * 64 + cr) * 64 + seg * 8] = v;
            }
            __syncthreads();
        }
    }
}

// ---------------------------------------------------------------------------
// K2b: merge 3 partials (1 f32 in-place + 2 bf16 tiles) + epilogue + prep_s.
// grid (128, 2): x = 32-px tile, y = b. block 256. (r11 exact)
// ---------------------------------------------------------------------------
__global__ __launch_bounds__(256) void merge_kernel(
    const float* __restrict__ x1, const float* __restrict__ x2,
    const short* __restrict__ featp, const float* __restrict__ lpart,
    const float* __restrict__ gamma_p,
    float* __restrict__ out1, float* __restrict__ out2,
    short* __restrict__ s_t)
{
    __shared__ short st[32 * 264];
    __shared__ float rls[2][32];
    const int tid = threadIdx.x;
    const int px0 = blockIdx.x * 32;
    const int b = blockIdx.y;
    const int nt = blockIdx.x >> 1;
    const int q32 = (blockIdx.x & 1) * 32;
    const float* xa_ = x1 + (size_t)b * CCH * N_PIX;
    const float* xb_ = x2 + (size_t)b * CCH * N_PIX;
    float* o1 = out1 + (size_t)b * CCH * N_PIX;   // holds pb=b   mh=0 f32 partial
    float* o2 = out2 + (size_t)b * CCH * N_PIX;   // holds pb=2+b mh=0 f32 partial
    const short* T10 = featp + (size_t)(b * 2 + 0) * (64 * 128 * 64) + (size_t)nt * (128 * 64);
    const short* T11 = featp + (size_t)(b * 2 + 1) * (64 * 128 * 64) + (size_t)nt * (128 * 64);
    const short* T20 = featp + (size_t)((2 + b) * 2 + 0) * (64 * 128 * 64) + (size_t)nt * (128 * 64);
    const short* T21 = featp + (size_t)((2 + b) * 2 + 1) * (64 * 128 * 64) + (size_t)nt * (128 * 64);

    if (tid < 64) {
        int h = tid >> 5, j = tid & 31;
        int pbh = h ? (2 + b) : b;
        float l = lpart[(size_t)(pbh * 3 + 0) * N_PIX + px0 + j]
                + lpart[(size_t)(pbh * 3 + 1) * N_PIX + px0 + j]
                + lpart[(size_t)(pbh * 3 + 2) * N_PIX + px0 + j];
        rls[h][j] = 1.0f / l;
    }
    __syncthreads();
    const float gmm = gamma_p[0];

    for (int idx = tid; idx < 2048; idx += 256) {
        int c = idx >> 3, p4 = idx & 7;
        size_t off = (size_t)c * N_PIX + px0 + p4 * 4;
        float4 va = *(const float4*)&xa_[off];
        float4 vb2 = *(const float4*)&xb_[off];
        float4 r1, r2;
        if (c < 128) {
            int toff = c * 64 + q32 + p4 * 4;
            float4 pa = *(const float4*)&o1[off];
            float4 pc = *(const float4*)&o2[off];
            float4 a1 = bf4_load(&T10[toff]);
            float4 a2 = bf4_load(&T11[toff]);
            float4 c1 = bf4_load(&T20[toff]);
            float4 c2 = bf4_load(&T21[toff]);
            r1.x = gmm * (pa.x + a1.x + a2.x) * rls[0][p4 * 4 + 0] + va.x;
            r1.y = gmm * (pa.y + a1.y + a2.y) * rls[0][p4 * 4 + 1] + va.y;
            r1.z = gmm * (pa.z + a1.z + a2.z) * rls[0][p4 * 4 + 2] + va.z;
            r1.w = gmm * (pa.w + a1.w + a2.w) * rls[0][p4 * 4 + 3] + va.w;
            r2.x = gmm * (pc.x + c1.x + c2.x) * rls[1][p4 * 4 + 0] + vb2.x;
            r2.y = gmm * (pc.y + c1.y + c2.y) * rls[1][p4 * 4 + 1] + vb2.y;
            r2.z = gmm * (pc.z + c1.z + c2.z) * rls[1][p4 * 4 + 2] + vb2.z;
            r2.w = gmm * (pc.w + c1.w + c2.w) * rls[1][p4 * 4 + 3] + vb2.w;
        } else {
            size_t offl = (size_t)(c - 128) * N_PIX + px0 + p4 * 4;
            float4 val = *(const float4*)&xa_[offl];
            float4 vbl = *(const float4*)&xb_[offl];
            r1.x = gmm * val.x + va.x; r1.y = gmm * val.y + va.y;
            r1.z = gmm * val.z + va.z; r1.w = gmm * val.w + va.w;
            r2.x = gmm * vbl.x + vb2.x; r2.y = gmm * vbl.y + vb2.y;
            r2.z = gmm * vbl.z + vb2.z; r2.w = gmm * vbl.w + vb2.w;
        }
        *(float4*)&o1[off] = r1;
        *(float4*)&o2[off] = r2;
        st[(p4 * 4 + 0) * 264 + c] = f2bf(r1.x + r2.x);
        st[(p4 * 4 + 1) * 264 + c] = f2bf(r1.y + r2.y);
        st[(p4 * 4 + 2) * 264 + c] = f2bf(r1.z + r2.z);
        st[(p4 * 4 + 3) * 264 + c] = f2bf(r1.w + r2.w);
    }
    __syncthreads();
    for (int idx = tid; idx < 1024; idx += 256) {
        int px = idx >> 5, seg = idx & 31;
        int4 v = *(const int4*)&st[px * 264 + seg * 8];
        *(int4*)&s_t[((size_t)b * N_PIX + px0 + px) * CCH + seg * 8] = v;
    }
}

// ---------------------------------------------------------------------------
// K3b: prep_w — blocks <288: Wcat -> bf16 A-fragment order.
//      blocks >=288 (40): pack Wq|Wk|Wv -> wqkv bf16 [160][256]. (r11 exact)
// ---------------------------------------------------------------------------
__global__ __launch_bounds__(256) void prep_w(
    const float* __restrict__ Wcat,
    const float* __restrict__ Wq, const float* __restrict__ Wk,
    const float* __restrict__ Wv,
    short* __restrict__ wfmt, short* __restrict__ wqkv)
{
    if (blockIdx.x < 288) {
        int idx = blockIdx.x * 256 + threadIdx.x;
        int lane = idx & 63;
        int ocg = (idx >> 6) & 15;
        int chunk = (idx >> 10) & 7;
        int tap = idx >> 13;
        int oc = ocg * 16 + (lane & 15);
        int ic0 = chunk * 32 + (lane >> 4) * 8;
        short8 v;
        #pragma unroll
        for (int j = 0; j < 8; ++j)
            v[j] = f2bf(Wcat[((size_t)oc * CCH + ic0 + j) * 9 + tap]);
        *(short8*)&wfmt[(size_t)idx * 8] = v;
    } else {
        int idx = (blockIdx.x - 288) * 1024 + threadIdx.x * 4;   // 0..40959
        int r = idx >> 8, c = idx & 255;
        const float* src;
        if (r < 16)      src = Wq + (size_t)r * CCH + c;
        else if (r < 32) src = Wk + (size_t)(r - 16) * CCH + c;
        else             src = Wv + (size_t)(r - 32) * CCH + c;
        float4 f = *(const float4*)src;
        short4 s;
        s.x = f2bf(f.x); s.y = f2bf(f.y); s.z = f2bf(f.z); s.w = f2bf(f.w);
        *(short4*)&wqkv[idx] = s;
    }
}

// ---------------------------------------------------------------------------
// K3c: conv implicit GEMM, oc-split 32/block for 4 blocks/CU (16 waves).
// grid 1024: oc_t = bx&7 (32 oc), pt = bx>>3: b = pt>>6, h0 = pt&63.
// Wave wv: px frag [wv*16,+16), 2 ocg (B-reuse 2/ds_read; latency-bound
// kernel trades B-reuse for 2x TLP). 3-row halo LDS 15.8KB.
// ---------------------------------------------------------------------------
__global__ __launch_bounds__(256, 4) void conv_mfma(
    const short* __restrict__ s_t, const short* __restrict__ wfmt,
    const float* __restrict__ bn_gamma, const float* __restrict__ bn_beta,
    float* __restrict__ feat)
{
    __shared__ short s_lds[198 * 40];   // 3 rows x 66 wi, pitch 40
    const int tid = threadIdx.x;
    const int lane = tid & 63;
    const int wv = tid >> 6;
    const int g = lane >> 4, l15 = lane & 15;

    const int bx = blockIdx.x;
    const int oc_t = bx & 7;
    const int pt = bx >> 3;
    const int b = pt >> 6;
    const int h0 = pt & 63;

    f32x4 acc[2] = {};   // [ocg]

    const short* sbase = s_t + (size_t)b * N_PIX * CCH;
    const short* wf = wfmt + ((size_t)(oc_t * 2) * 64 + lane) * 8;

    for (int ci = 0; ci < 8; ++ci) {
        const int ic0 = ci * 32;
        __syncthreads();
        for (int idx = tid; idx < 792; idx += 256) {
            int seg = idx & 3, pos = idx >> 2;      // pos = row*66 + wi
            int row = pos / 66, wi = pos - row * 66;
            int hr = h0 - 1 + row, w = wi - 1;
            int4 val = {0, 0, 0, 0};
            if (hr >= 0 && hr < 64 && (unsigned)w < 64u)
                val = *(const int4*)&sbase[((size_t)(hr * 64 + w)) * CCH + ic0 + seg * 8];
            *(int4*)&s_lds[pos * 40 + seg * 8] = val;
        }
        __syncthreads();

        const short* wfc = wf + (size_t)ci * 8192;
        bf16x8 a0[2], a1[2];
        #pragma unroll
        for (int j = 0; j < 2; ++j) a0[j] = *(const bf16x8*)&wfc[j * 512];

        for (int tap = 0; tap < 9; ++tap) {
            bf16x8* ac = (tap & 1) ? a1 : a0;
            bf16x8* an = (tap & 1) ? a0 : a1;
            if (tap < 8) {
                const short* wfn = wfc + (size_t)(tap + 1) * 65536;
                #pragma unroll
                for (int j = 0; j < 2; ++j) an[j] = *(const bf16x8*)&wfn[j * 512];
            }
            int ky = (tap >= 6) ? 2 : (tap >= 3 ? 1 : 0);
            int kx = tap - ky * 3;
            bf16x8 bb = *(const bf16x8*)
                &s_lds[(ky * 66 + wv * 16 + l15 + kx) * 40 + g * 8];
            #pragma unroll
            for (int j = 0; j < 2; ++j)
                acc[j] = __builtin_amdgcn_mfma_f32_16x16x32_bf16(
                    ac[j], bb, acc[j], 0, 0, 0);
        }
    }

    const float inv = rsqrtf(1.0f + 1e-5f);
    const int wcol = wv * 16 + l15;
    #pragma unroll
    for (int j = 0; j < 2; ++j) {
        #pragma unroll
        for (int r = 0; r < 4; ++r) {
            int oc = oc_t * 32 + j * 16 + g * 4 + r;
            float y = acc[j][r] * (bn_gamma[oc] * inv) + bn_beta[oc];
            feat[((size_t)b * CCH + oc) * N_PIX + h0 * 64 + wcol] = fmaxf(y, 0.f);
        }
    }
}

// ---------------------------------------------------------------------------
extern "C" void kernel_launch(void* const* d_in, const int* in_sizes, int n_in,
                              void* d_out, int out_size, void* d_ws, size_t ws_size,
                              hipStream_t stream) {
    const float* x1    = (const float*)d_in[0];
    const float* x2    = (const float*)d_in[1];
    const float* Wq    = (const float*)d_in[2];
    const float* bq    = (const float*)d_in[3];
    const float* Wk    = (const float*)d_in[4];
    const float* bk    = (const float*)d_in[5];
    const float* Wv    = (const float*)d_in[6];
    const float* bv    = (const float*)d_in[7];
    const float* gamma = (const float*)d_in[8];
    const float* Wcat  = (const float*)d_in[9];
    const float* bng   = (const float*)d_in[10];
    const float* bnb   = (const float*)d_in[11];

    float* out  = (float*)d_out;
    float* feat = out;                    // hosts 8 bf16 tiled partial slots pre-conv
    float* out1 = out + 2097152;
    float* out2 = out + 4194304;

    short* ws   = (short*)d_ws;
    short* qb   = ws;                     // 262144 shorts
    short* kb   = ws + 262144;            // 262144
    short* vb   = ws + 524288;            // 2097152
    short* s_t  = ws + 2621440;           // 2097152
    short* wfmt = ws + 4718592;           // 589824
    float* lp   = (float*)(ws + 5308416); // 12*4096 f32 l-partials
    short* wqkv = s_t;                    // aliases s_t (dead until merge writes it)

    prep_w<<<328, 256, 0, stream>>>(Wcat, Wq, Wk, Wv, wfmt, wqkv);
    qkv_kernel<<<dim3(64, 4), 512, 0, stream>>>(x1, x2, wqkv, bq, bk, bv, qb, kb, vb);
    attn_kernel<<<768, 256, 0, stream>>>(qb, kb, vb, out1, out2, (short*)feat, lp);
    merge_kernel<<<dim3(128, 2), 256, 0, stream>>>(x1, x2, (const short*)feat, lp, gamma, out1, out2, s_t);
    conv_mfma<<<1024, 256, 0, stream>>>(s_t, wfmt, bng, bnb, feat);
}

// Round 18
// 101.791 us; speedup vs baseline: 1.2652x; 1.2652x over previous
//
#include <hip/hip_runtime.h>

#define N_PIX 4096
#define CCH 256
#define DV 128

typedef __attribute__((ext_vector_type(8))) short bf16x8;
typedef __attribute__((ext_vector_type(4))) float f32x4;
typedef __attribute__((ext_vector_type(8))) short short8;

__device__ __forceinline__ short f2bf(float f) {
    unsigned u = __builtin_bit_cast(unsigned, f);
    u += 0x7fffu + ((u >> 16) & 1u);
    return (short)(u >> 16);
}

__device__ __forceinline__ float4 bf4_load(const short* p) {
    short4 s = *(const short4*)p;
    float4 f;
    f.x = __builtin_bit_cast(float, (unsigned)((unsigned short)s.x) << 16);
    f.y = __builtin_bit_cast(float, (unsigned)((unsigned short)s.y) << 16);
    f.z = __builtin_bit_cast(float, (unsigned)((unsigned short)s.z) << 16);
    f.w = __builtin_bit_cast(float, (unsigned)((unsigned short)s.w) << 16);
    return f;
}

// ---------------------------------------------------------------------------
// K1: fused 1x1 convs as ONE bf16 MFMA GEMM (r11 exact).
// ---------------------------------------------------------------------------
__global__ __launch_bounds__(512) void qkv_kernel(
    const float* __restrict__ x1, const float* __restrict__ x2,
    const short* __restrict__ wqkv,
    const float* __restrict__ bq, const float* __restrict__ bk,
    const float* __restrict__ bv,
    short* __restrict__ qb, short* __restrict__ kb, short* __restrict__ vb)
{
    __shared__ short xT[64][68];   // [px][c-chunk], pitch 68 shorts

    const int tid = threadIdx.x;
    const int lane = tid & 63;
    const int w = tid >> 6;
    const int g = lane >> 4, l15 = lane & 15;
    const int n0 = blockIdx.x * 64;
    const int ib = blockIdx.y;
    const int i = ib >> 1, b = ib & 1;
    const float* x = (i == 0 ? x1 : x2) + (size_t)b * CCH * N_PIX;

    const int px2 = tid & 31, c4 = tid >> 5;
    const int rhalf = (w >> 2) * 80;

    f32x4 acc[5];
    #pragma unroll
    for (int jl = 0; jl < 5; ++jl) {
        int rbase = rhalf + jl * 16;
        float bias;
        if (rbase == 0)       bias = bq[l15];
        else if (rbase == 16) bias = bk[l15];
        else                  bias = bv[rbase - 32 + l15];
        acc[jl] = (f32x4){bias, bias, bias, bias};
    }

    float2 xr[4];
    {
        #pragma unroll
        for (int jj = 0; jj < 4; ++jj)
            xr[jj] = *(const float2*)&x[(size_t)(c4 * 4 + jj) * N_PIX + n0 + px2 * 2];
    }

    for (int ci = 0; ci < 4; ++ci) {   // 4 chunks x 64 c = K 256
        __syncthreads();
        {
            short4 w0, w1;
            w0.x = f2bf(xr[0].x); w0.y = f2bf(xr[1].x); w0.z = f2bf(xr[2].x); w0.w = f2bf(xr[3].x);
            w1.x = f2bf(xr[0].y); w1.y = f2bf(xr[1].y); w1.z = f2bf(xr[2].y); w1.w = f2bf(xr[3].y);
            *(short4*)&xT[px2 * 2 + 0][c4 * 4] = w0;
            *(short4*)&xT[px2 * 2 + 1][c4 * 4] = w1;
        }
        __syncthreads();
        if (ci < 3) {
            #pragma unroll
            for (int jj = 0; jj < 4; ++jj)
                xr[jj] = *(const float2*)
                    &x[(size_t)((ci + 1) * 64 + c4 * 4 + jj) * N_PIX + n0 + px2 * 2];
        }
        bf16x8 a0 = *(const bf16x8*)&xT[(w & 3) * 16 + l15][g * 8];
        bf16x8 a1 = *(const bf16x8*)&xT[(w & 3) * 16 + l15][32 + g * 8];
        #pragma unroll
        for (int jl = 0; jl < 5; ++jl) {
            int rbase = rhalf + jl * 16;
            const short* wrow = wqkv + (size_t)(rbase + l15) * CCH + ci * 64;
            bf16x8 b0 = *(const bf16x8*)&wrow[g * 8];
            bf16x8 b1 = *(const bf16x8*)&wrow[32 + g * 8];
            acc[jl] = __builtin_amdgcn_mfma_f32_16x16x32_bf16(a0, b0, acc[jl], 0, 0, 0);
            acc[jl] = __builtin_amdgcn_mfma_f32_16x16x32_bf16(a1, b1, acc[jl], 0, 0, 0);
        }
    }

    const int px_base = n0 + (w & 3) * 16 + g * 4;
    #pragma unroll
    for (int jl = 0; jl < 5; ++jl) {
        int rbase = rhalf + jl * 16;
        if (rbase == 0) {
            #pragma unroll
            for (int rr = 0; rr < 4; ++rr)
                qb[((size_t)ib * N_PIX + px_base + rr) * 16 + l15] = f2bf(acc[jl][rr]);
        } else if (rbase == 16) {
            #pragma unroll
            for (int rr = 0; rr < 4; ++rr)
                kb[((size_t)ib * N_PIX + px_base + rr) * 16 + l15] = f2bf(acc[jl][rr]);
        } else {
            int c = rbase - 32 + l15;
            short4 s;
            s.x = f2bf(acc[jl][0]); s.y = f2bf(acc[jl][1]);
            s.z = f2bf(acc[jl][2]); s.w = f2bf(acc[jl][3]);
            *(short4*)&vb[((size_t)ib * DV + c) * N_PIX + px_base] = s;
        }
    }
}

// ---------------------------------------------------------------------------
// K2: MFMA flash attention, V-in-registers, 3-way m-split (r11 exact —
// 46.5 µs proven: pitch 72 = 16B-aligned b128, K staged to LDS by waves
// 192+, double-buffered V regs, 2 barriers/chunk, 64 VGPR no-spill).
// grid 768: pb = bid&3, mh = (bid>>2)%3, nt = bid/12. 3 blocks/CU.
// Partials: mh=0 -> f32 in out1/out2 c<128 (merged in place);
// mh=1,2 -> bf16 tiled [slot=pb*2+(mh-1)][nt][c][64] in feat region,
// written via LDS repack (full-line int4 stores).
// ---------------------------------------------------------------------------
__global__ __launch_bounds__(256, 4) void attn_kernel(
    const short* __restrict__ qg, const short* __restrict__ kg,
    const short* __restrict__ vg,
    float* __restrict__ out1, float* __restrict__ out2,
    short* __restrict__ featp, float* __restrict__ lpart)
{
    __shared__ short k_lds[64 * 24];   // [m][d], pitch 24 shorts (48B)
    __shared__ short p_lds[64 * 72];   // [n][m] in loop; [c][66] repack at end

    const int tid = threadIdx.x;
    const int lane = tid & 63;
    const int w = tid >> 6;
    const int gk = lane >> 4;
    const int l15 = lane & 15;

    const int B_ = blockIdx.x;
    const int pb = B_ & 3;
    const int mh = (B_ >> 2) % 3;
    const int nt = B_ / 12;
    const int n0 = nt * 64;
    const int br = pb >> 1, b = pb & 1;
    const int tstart = mh * 22;
    const int tend = (mh == 2) ? 64 : tstart + 22;   // 22/22/20, all even

    const short* qp = qg + (size_t)pb * N_PIX * 16;
    const short* kp = kg + (size_t)((br ^ 1) * 2 + b) * N_PIX * 16;
    const short* vp = vg + (size_t)pb * DV * N_PIX;

    bf16x8 aq = {};
    if (lane < 32)
        aq = *(const bf16x8*)&qp[(size_t)(n0 + w * 16 + l15) * 16 + gk * 8];

    f32x4 acc[2][4];
    #pragma unroll
    for (int cc = 0; cc < 2; ++cc)
        #pragma unroll
        for (int nb = 0; nb < 4; ++nb) acc[cc][nb] = (f32x4){0.f, 0.f, 0.f, 0.f};
    float lsum[4] = {0.f, 0.f, 0.f, 0.f};

    const short* vbase = vp + (size_t)(w * 32 + l15) * N_PIX + gk * 8;
    const int krow = tid - 192;

    int4 vbuf0[4], vbuf1[4];
    int4 kr0 = {}, kr1 = {};

    {   // prologue: chunk tstart -> V regs, K LDS
        #pragma unroll
        for (int cc = 0; cc < 2; ++cc)
            #pragma unroll
            for (int m2 = 0; m2 < 2; ++m2)
                vbuf0[cc * 2 + m2] = *(const int4*)
                    &vbase[(size_t)cc * 16 * N_PIX + tstart * 64 + m2 * 32];
        if (tid >= 192) {
            kr0 = *(const int4*)&kp[(size_t)(tstart * 64 + krow) * 16];
            kr1 = *(const int4*)&kp[(size_t)(tstart * 64 + krow) * 16 + 8];
            *(int4*)&k_lds[krow * 24] = kr0;
            *(int4*)&k_lds[krow * 24 + 8] = kr1;
        }
        __syncthreads();
    }

    for (int t0 = tstart; t0 < tend; t0 += 2) {
        #pragma unroll
        for (int half = 0; half < 2; ++half) {
            const int t = t0 + half;
            int4* vcur = half ? vbuf1 : vbuf0;
            int4* vnxt = half ? vbuf0 : vbuf1;
            if (t + 1 < tend) {
                #pragma unroll
                for (int cc = 0; cc < 2; ++cc)
                    #pragma unroll
                    for (int m2 = 0; m2 < 2; ++m2)
                        vnxt[cc * 2 + m2] = *(const int4*)
                            &vbase[(size_t)cc * 16 * N_PIX + (t + 1) * 64 + m2 * 32];
                if (tid >= 192) {
                    kr0 = *(const int4*)&kp[(size_t)((t + 1) * 64 + krow) * 16];
                    kr1 = *(const int4*)&kp[(size_t)((t + 1) * 64 + krow) * 16 + 8];
                }
            }
            #pragma unroll
            for (int h = 0; h < 4; ++h) {
                bf16x8 bk_ = {};
                if (lane < 32)
                    bk_ = *(const bf16x8*)&k_lds[(h * 16 + l15) * 24 + gk * 8];
                f32x4 s = __builtin_amdgcn_mfma_f32_16x16x32_bf16(
                    aq, bk_, (f32x4){0.f, 0.f, 0.f, 0.f}, 0, 0, 0);
                #pragma unroll
                for (int rr = 0; rr < 4; ++rr) {
                    float e = __expf(s[rr] * 0.25f);
                    lsum[rr] += e;
                    unsigned u = __builtin_bit_cast(unsigned, e);
                    p_lds[(w * 16 + gk * 4 + rr) * 72 + h * 16 + l15] = (short)(u >> 16);
                }
            }
            __syncthreads();
            if (t + 1 < tend && tid >= 192) {
                *(int4*)&k_lds[krow * 24] = kr0;
                *(int4*)&k_lds[krow * 24 + 8] = kr1;
            }
            __builtin_amdgcn_s_setprio(1);
            #pragma unroll
            for (int m2 = 0; m2 < 2; ++m2) {
                #pragma unroll
                for (int nb = 0; nb < 4; ++nb) {
                    bf16x8 bp = *(const bf16x8*)&p_lds[(nb * 16 + l15) * 72 + m2 * 32 + gk * 8];
                    #pragma unroll
                    for (int cc = 0; cc < 2; ++cc) {
                        bf16x8 av = __builtin_bit_cast(bf16x8, vcur[cc * 2 + m2]);
                        acc[cc][nb] = __builtin_amdgcn_mfma_f32_16x16x32_bf16(
                            av, bp, acc[cc][nb], 0, 0, 0);
                    }
                }
            }
            __builtin_amdgcn_s_setprio(0);
            __syncthreads();
        }
    }

    #pragma unroll
    for (int rr = 0; rr < 4; ++rr) {
        float v = lsum[rr];
        v += __shfl_xor(v, 1); v += __shfl_xor(v, 2);
        v += __shfl_xor(v, 4); v += __shfl_xor(v, 8);
        lsum[rr] = v;
    }
    if (l15 == 0) {
        #pragma unroll
        for (int rr = 0; rr < 4; ++rr)
            lpart[(size_t)(pb * 3 + mh) * N_PIX + n0 + w * 16 + gk * 4 + rr] = lsum[rr];
    }

    if (mh == 0) {   // f32 partial at final location (c<128 of out1/out2)
        float* Od = (br ? out2 : out1) + (size_t)b * CCH * N_PIX;
        #pragma unroll
        for (int cc = 0; cc < 2; ++cc)
            #pragma unroll
            for (int nb = 0; nb < 4; ++nb)
                #pragma unroll
                for (int rr = 0; rr < 4; ++rr) {
                    int c = w * 32 + cc * 16 + gk * 4 + rr;
                    Od[(size_t)c * N_PIX + n0 + nb * 16 + l15] = acc[cc][nb][rr];
                }
    } else {
        // bf16 tiled slot, via LDS repack -> full-line int4 stores
        short* Ps = featp + (size_t)(pb * 2 + (mh - 1)) * (64 * 128 * 64)
                          + (size_t)nt * (128 * 64);
        #pragma unroll
        for (int chalf = 0; chalf < 2; ++chalf) {
            if ((w >> 1) == chalf) {   // waves 0,1 -> c 0..63; waves 2,3 -> 64..127
                int crel_base = (w & 1) * 32;
                #pragma unroll
                for (int cc = 0; cc < 2; ++cc)
                    #pragma unroll
                    for (int nb = 0; nb < 4; ++nb)
                        #pragma unroll
                        for (int rr = 0; rr < 4; ++rr) {
                            int crel = crel_base + cc * 16 + gk * 4 + rr;
                            p_lds[crel * 66 + nb * 16 + l15] = f2bf(acc[cc][nb][rr]);
                        }
            }
            __syncthreads();
            for (int idx = tid; idx < 512; idx += 256) {
                int cr = idx >> 3, seg = idx & 7;
                int4 v = *(const int4*)&p_lds[cr * 66 + seg * 8];
                *(int4*)&Ps[(size_t)(chalf * 64 + cr) * 64 + seg * 8] = v;
            }
            __syncthreads();
        }
    }
}

// ---------------------------------------------------------------------------
// K2b: merge 3 partials (1 f32 in-place + 2 bf16 tiles) + epilogue + prep_s.
// grid (128, 2): x = 32-px tile, y = b. block 256. (r11 exact)
// ---------------------------------------------------------------------------
__global__ __launch_bounds__(256) void merge_kernel(
    const float* __restrict__ x1, const float* __restrict__ x2,
    const short* __restrict__ featp, const float* __restrict__ lpart,
    const float* __restrict__ gamma_p,
    float* __restrict__ out1, float* __restrict__ out2,
    short* __restrict__ s_t)
{
    __shared__ short st[32 * 264];
    __shared__ float rls[2][32];
    const int tid = threadIdx.x;
    const int px0 = blockIdx.x * 32;
    const int b = blockIdx.y;
    const int nt = blockIdx.x >> 1;
    const int q32 = (blockIdx.x & 1) * 32;
    const float* xa_ = x1 + (size_t)b * CCH * N_PIX;
    const float* xb_ = x2 + (size_t)b * CCH * N_PIX;
    float* o1 = out1 + (size_t)b * CCH * N_PIX;   // holds pb=b   mh=0 f32 partial
    float* o2 = out2 + (size_t)b * CCH * N_PIX;   // holds pb=2+b mh=0 f32 partial
    const short* T10 = featp + (size_t)(b * 2 + 0) * (64 * 128 * 64) + (size_t)nt * (128 * 64);
    const short* T11 = featp + (size_t)(b * 2 + 1) * (64 * 128 * 64) + (size_t)nt * (128 * 64);
    const short* T20 = featp + (size_t)((2 + b) * 2 + 0) * (64 * 128 * 64) + (size_t)nt * (128 * 64);
    const short* T21 = featp + (size_t)((2 + b) * 2 + 1) * (64 * 128 * 64) + (size_t)nt * (128 * 64);

    if (tid < 64) {
        int h = tid >> 5, j = tid & 31;
        int pbh = h ? (2 + b) : b;
        float l = lpart[(size_t)(pbh * 3 + 0) * N_PIX + px0 + j]
                + lpart[(size_t)(pbh * 3 + 1) * N_PIX + px0 + j]
                + lpart[(size_t)(pbh * 3 + 2) * N_PIX + px0 + j];
        rls[h][j] = 1.0f / l;
    }
    __syncthreads();
    const float gmm = gamma_p[0];

    for (int idx = tid; idx < 2048; idx += 256) {
        int c = idx >> 3, p4 = idx & 7;
        size_t off = (size_t)c * N_PIX + px0 + p4 * 4;
        float4 va = *(const float4*)&xa_[off];
        float4 vb2 = *(const float4*)&xb_[off];
        float4 r1, r2;
        if (c < 128) {
            int toff = c * 64 + q32 + p4 * 4;
            float4 pa = *(const float4*)&o1[off];
            float4 pc = *(const float4*)&o2[off];
            float4 a1 = bf4_load(&T10[toff]);
            float4 a2 = bf4_load(&T11[toff]);
            float4 c1 = bf4_load(&T20[toff]);
            float4 c2 = bf4_load(&T21[toff]);
            r1.x = gmm * (pa.x + a1.x + a2.x) * rls[0][p4 * 4 + 0] + va.x;
            r1.y = gmm * (pa.y + a1.y + a2.y) * rls[0][p4 * 4 + 1] + va.y;
            r1.z = gmm * (pa.z + a1.z + a2.z) * rls[0][p4 * 4 + 2] + va.z;
            r1.w = gmm * (pa.w + a1.w + a2.w) * rls[0][p4 * 4 + 3] + va.w;
            r2.x = gmm * (pc.x + c1.x + c2.x) * rls[1][p4 * 4 + 0] + vb2.x;
            r2.y = gmm * (pc.y + c1.y + c2.y) * rls[1][p4 * 4 + 1] + vb2.y;
            r2.z = gmm * (pc.z + c1.z + c2.z) * rls[1][p4 * 4 + 2] + vb2.z;
            r2.w = gmm * (pc.w + c1.w + c2.w) * rls[1][p4 * 4 + 3] + vb2.w;
        } else {
            size_t offl = (size_t)(c - 128) * N_PIX + px0 + p4 * 4;
            float4 val = *(const float4*)&xa_[offl];
            float4 vbl = *(const float4*)&xb_[offl];
            r1.x = gmm * val.x + va.x; r1.y = gmm * val.y + va.y;
            r1.z = gmm * val.z + va.z; r1.w = gmm * val.w + va.w;
            r2.x = gmm * vbl.x + vb2.x; r2.y = gmm * vbl.y + vb2.y;
            r2.z = gmm * vbl.z + vb2.z; r2.w = gmm * vbl.w + vb2.w;
        }
        *(float4*)&o1[off] = r1;
        *(float4*)&o2[off] = r2;
        st[(p4 * 4 + 0) * 264 + c] = f2bf(r1.x + r2.x);
        st[(p4 * 4 + 1) * 264 + c] = f2bf(r1.y + r2.y);
        st[(p4 * 4 + 2) * 264 + c] = f2bf(r1.z + r2.z);
        st[(p4 * 4 + 3) * 264 + c] = f2bf(r1.w + r2.w);
    }
    __syncthreads();
    for (int idx = tid; idx < 1024; idx += 256) {
        int px = idx >> 5, seg = idx & 31;
        int4 v = *(const int4*)&st[px * 264 + seg * 8];
        *(int4*)&s_t[((size_t)b * N_PIX + px0 + px) * CCH + seg * 8] = v;
    }
}

// ---------------------------------------------------------------------------
// K3b: prep_w — blocks <288: Wcat -> bf16 A-fragment order.
//      blocks >=288 (40): pack Wq|Wk|Wv -> wqkv bf16 [160][256]. (r11 exact)
// ---------------------------------------------------------------------------
__global__ __launch_bounds__(256) void prep_w(
    const float* __restrict__ Wcat,
    const float* __restrict__ Wq, const float* __restrict__ Wk,
    const float* __restrict__ Wv,
    short* __restrict__ wfmt, short* __restrict__ wqkv)
{
    if (blockIdx.x < 288) {
        int idx = blockIdx.x * 256 + threadIdx.x;
        int lane = idx & 63;
        int ocg = (idx >> 6) & 15;
        int chunk = (idx >> 10) & 7;
        int tap = idx >> 13;
        int oc = ocg * 16 + (lane & 15);
        int ic0 = chunk * 32 + (lane >> 4) * 8;
        short8 v;
        #pragma unroll
        for (int j = 0; j < 8; ++j)
            v[j] = f2bf(Wcat[((size_t)oc * CCH + ic0 + j) * 9 + tap]);
        *(short8*)&wfmt[(size_t)idx * 8] = v;
    } else {
        int idx = (blockIdx.x - 288) * 1024 + threadIdx.x * 4;   // 0..40959
        int r = idx >> 8, c = idx & 255;
        const float* src;
        if (r < 16)      src = Wq + (size_t)r * CCH + c;
        else if (r < 32) src = Wk + (size_t)(r - 16) * CCH + c;
        else             src = Wv + (size_t)(r - 32) * CCH + c;
        float4 f = *(const float4*)src;
        short4 s;
        s.x = f2bf(f.x); s.y = f2bf(f.y); s.z = f2bf(f.z); s.w = f2bf(f.w);
        *(short4*)&wqkv[idx] = s;
    }
}

// ---------------------------------------------------------------------------
// K3c: conv implicit GEMM, oc-split 32/block for 4 blocks/CU (16 waves) —
// r17's validated conv improvement (~4-5 µs via subtraction attribution).
// grid 1024: oc_t = bx&7 (32 oc), pt = bx>>3: b = pt>>6, h0 = pt&63.
// ---------------------------------------------------------------------------
__global__ __launch_bounds__(256, 4) void conv_mfma(
    const short* __restrict__ s_t, const short* __restrict__ wfmt,
    const float* __restrict__ bn_gamma, const float* __restrict__ bn_beta,
    float* __restrict__ feat)
{
    __shared__ short s_lds[198 * 40];   // 3 rows x 66 wi, pitch 40
    const int tid = threadIdx.x;
    const int lane = tid & 63;
    const int wv = tid >> 6;
    const int g = lane >> 4, l15 = lane & 15;

    const int bx = blockIdx.x;
    const int oc_t = bx & 7;
    const int pt = bx >> 3;
    const int b = pt >> 6;
    const int h0 = pt & 63;

    f32x4 acc[2] = {};   // [ocg]

    const short* sbase = s_t + (size_t)b * N_PIX * CCH;
    const short* wf = wfmt + ((size_t)(oc_t * 2) * 64 + lane) * 8;

    for (int ci = 0; ci < 8; ++ci) {
        const int ic0 = ci * 32;
        __syncthreads();
        for (int idx = tid; idx < 792; idx += 256) {
            int seg = idx & 3, pos = idx >> 2;      // pos = row*66 + wi
            int row = pos / 66, wi = pos - row * 66;
            int hr = h0 - 1 + row, w = wi - 1;
            int4 val = {0, 0, 0, 0};
            if (hr >= 0 && hr < 64 && (unsigned)w < 64u)
                val = *(const int4*)&sbase[((size_t)(hr * 64 + w)) * CCH + ic0 + seg * 8];
            *(int4*)&s_lds[pos * 40 + seg * 8] = val;
        }
        __syncthreads();

        const short* wfc = wf + (size_t)ci * 8192;
        bf16x8 a0[2], a1[2];
        #pragma unroll
        for (int j = 0; j < 2; ++j) a0[j] = *(const bf16x8*)&wfc[j * 512];

        for (int tap = 0; tap < 9; ++tap) {
            bf16x8* ac = (tap & 1) ? a1 : a0;
            bf16x8* an = (tap & 1) ? a0 : a1;
            if (tap < 8) {
                const short* wfn = wfc + (size_t)(tap + 1) * 65536;
                #pragma unroll
                for (int j = 0; j < 2; ++j) an[j] = *(const bf16x8*)&wfn[j * 512];
            }
            int ky = (tap >= 6) ? 2 : (tap >= 3 ? 1 : 0);
            int kx = tap - ky * 3;
            bf16x8 bb = *(const bf16x8*)
                &s_lds[(ky * 66 + wv * 16 + l15 + kx) * 40 + g * 8];
            #pragma unroll
            for (int j = 0; j < 2; ++j)
                acc[j] = __builtin_amdgcn_mfma_f32_16x16x32_bf16(
                    ac[j], bb, acc[j], 0, 0, 0);
        }
    }

    const float inv = rsqrtf(1.0f + 1e-5f);
    const int wcol = wv * 16 + l15;
    #pragma unroll
    for (int j = 0; j < 2; ++j) {
        #pragma unroll
        for (int r = 0; r < 4; ++r) {
            int oc = oc_t * 32 + j * 16 + g * 4 + r;
            float y = acc[j][r] * (bn_gamma[oc] * inv) + bn_beta[oc];
            feat[((size_t)b * CCH + oc) * N_PIX + h0 * 64 + wcol] = fmaxf(y, 0.f);
        }
    }
}

// ---------------------------------------------------------------------------
extern "C" void kernel_launch(void* const* d_in, const int* in_sizes, int n_in,
                              void* d_out, int out_size, void* d_ws, size_t ws_size,
                              hipStream_t stream) {
    const float* x1    = (const float*)d_in[0];
    const float* x2    = (const float*)d_in[1];
    const float* Wq    = (const float*)d_in[2];
    const float* bq    = (const float*)d_in[3];
    const float* Wk    = (const float*)d_in[4];
    const float* bk    = (const float*)d_in[5];
    const float* Wv    = (const float*)d_in[6];
    const float* bv    = (const float*)d_in[7];
    const float* gamma = (const float*)d_in[8];
    const float* Wcat  = (const float*)d_in[9];
    const float* bng   = (const float*)d_in[10];
    const float* bnb   = (const float*)d_in[11];

    float* out  = (float*)d_out;
    float* feat = out;                    // hosts 8 bf16 tiled partial slots pre-conv
    float* out1 = out + 2097152;
    float* out2 = out + 4194304;

    short* ws   = (short*)d_ws;
    short* qb   = ws;                     // 262144 shorts
    short* kb   = ws + 262144;            // 262144
    short* vb   = ws + 524288;            // 2097152
    short* s_t  = ws + 2621440;           // 2097152
    short* wfmt = ws + 4718592;           // 589824
    float* lp   = (float*)(ws + 5308416); // 12*4096 f32 l-partials
    short* wqkv = s_t;                    // aliases s_t (dead until merge writes it)

    prep_w<<<328, 256, 0, stream>>>(Wcat, Wq, Wk, Wv, wfmt, wqkv);
    qkv_kernel<<<dim3(64, 4), 512, 0, stream>>>(x1, x2, wqkv, bq, bk, bv, qb, kb, vb);
    attn_kernel<<<768, 256, 0, stream>>>(qb, kb, vb, out1, out2, (short*)feat, lp);
    merge_kernel<<<dim3(128, 2), 256, 0, stream>>>(x1, x2, (const short*)feat, lp, gamma, out1, out2, s_t);
    conv_mfma<<<1024, 256, 0, stream>>>(s_t, wfmt, bng, bnb, feat);
}

// Round 19
// 101.738 us; speedup vs baseline: 1.2658x; 1.0005x over previous
//
#include <hip/hip_runtime.h>

#define N_PIX 4096
#define CCH 256
#define DV 128

typedef __attribute__((ext_vector_type(8))) short bf16x8;
typedef __attribute__((ext_vector_type(4))) float f32x4;
typedef __attribute__((ext_vector_type(8))) short short8;

__device__ __forceinline__ short f2bf(float f) {
    unsigned u = __builtin_bit_cast(unsigned, f);
    u += 0x7fffu + ((u >> 16) & 1u);
    return (short)(u >> 16);
}

__device__ __forceinline__ float4 bf4_load(const short* p) {
    short4 s = *(const short4*)p;
    float4 f;
    f.x = __builtin_bit_cast(float, (unsigned)((unsigned short)s.x) << 16);
    f.y = __builtin_bit_cast(float, (unsigned)((unsigned short)s.y) << 16);
    f.z = __builtin_bit_cast(float, (unsigned)((unsigned short)s.z) << 16);
    f.w = __builtin_bit_cast(float, (unsigned)((unsigned short)s.w) << 16);
    return f;
}

// ---------------------------------------------------------------------------
// K1: fused 1x1 convs as ONE bf16 MFMA GEMM (r11 exact).
// ---------------------------------------------------------------------------
__global__ __launch_bounds__(512) void qkv_kernel(
    const float* __restrict__ x1, const float* __restrict__ x2,
    const short* __restrict__ wqkv,
    const float* __restrict__ bq, const float* __restrict__ bk,
    const float* __restrict__ bv,
    short* __restrict__ qb, short* __restrict__ kb, short* __restrict__ vb)
{
    __shared__ short xT[64][68];   // [px][c-chunk], pitch 68 shorts

    const int tid = threadIdx.x;
    const int lane = tid & 63;
    const int w = tid >> 6;
    const int g = lane >> 4, l15 = lane & 15;
    const int n0 = blockIdx.x * 64;
    const int ib = blockIdx.y;
    const int i = ib >> 1, b = ib & 1;
    const float* x = (i == 0 ? x1 : x2) + (size_t)b * CCH * N_PIX;

    const int px2 = tid & 31, c4 = tid >> 5;
    const int rhalf = (w >> 2) * 80;

    f32x4 acc[5];
    #pragma unroll
    for (int jl = 0; jl < 5; ++jl) {
        int rbase = rhalf + jl * 16;
        float bias;
        if (rbase == 0)       bias = bq[l15];
        else if (rbase == 16) bias = bk[l15];
        else                  bias = bv[rbase - 32 + l15];
        acc[jl] = (f32x4){bias, bias, bias, bias};
    }

    float2 xr[4];
    {
        #pragma unroll
        for (int jj = 0; jj < 4; ++jj)
            xr[jj] = *(const float2*)&x[(size_t)(c4 * 4 + jj) * N_PIX + n0 + px2 * 2];
    }

    for (int ci = 0; ci < 4; ++ci) {   // 4 chunks x 64 c = K 256
        __syncthreads();
        {
            short4 w0, w1;
            w0.x = f2bf(xr[0].x); w0.y = f2bf(xr[1].x); w0.z = f2bf(xr[2].x); w0.w = f2bf(xr[3].x);
            w1.x = f2bf(xr[0].y); w1.y = f2bf(xr[1].y); w1.z = f2bf(xr[2].y); w1.w = f2bf(xr[3].y);
            *(short4*)&xT[px2 * 2 + 0][c4 * 4] = w0;
            *(short4*)&xT[px2 * 2 + 1][c4 * 4] = w1;
        }
        __syncthreads();
        if (ci < 3) {
            #pragma unroll
            for (int jj = 0; jj < 4; ++jj)
                xr[jj] = *(const float2*)
                    &x[(size_t)((ci + 1) * 64 + c4 * 4 + jj) * N_PIX + n0 + px2 * 2];
        }
        bf16x8 a0 = *(const bf16x8*)&xT[(w & 3) * 16 + l15][g * 8];
        bf16x8 a1 = *(const bf16x8*)&xT[(w & 3) * 16 + l15][32 + g * 8];
        #pragma unroll
        for (int jl = 0; jl < 5; ++jl) {
            int rbase = rhalf + jl * 16;
            const short* wrow = wqkv + (size_t)(rbase + l15) * CCH + ci * 64;
            bf16x8 b0 = *(const bf16x8*)&wrow[g * 8];
            bf16x8 b1 = *(const bf16x8*)&wrow[32 + g * 8];
            acc[jl] = __builtin_amdgcn_mfma_f32_16x16x32_bf16(a0, b0, acc[jl], 0, 0, 0);
            acc[jl] = __builtin_amdgcn_mfma_f32_16x16x32_bf16(a1, b1, acc[jl], 0, 0, 0);
        }
    }

    const int px_base = n0 + (w & 3) * 16 + g * 4;
    #pragma unroll
    for (int jl = 0; jl < 5; ++jl) {
        int rbase = rhalf + jl * 16;
        if (rbase == 0) {
            #pragma unroll
            for (int rr = 0; rr < 4; ++rr)
                qb[((size_t)ib * N_PIX + px_base + rr) * 16 + l15] = f2bf(acc[jl][rr]);
        } else if (rbase == 16) {
            #pragma unroll
            for (int rr = 0; rr < 4; ++rr)
                kb[((size_t)ib * N_PIX + px_base + rr) * 16 + l15] = f2bf(acc[jl][rr]);
        } else {
            int c = rbase - 32 + l15;
            short4 s;
            s.x = f2bf(acc[jl][0]); s.y = f2bf(acc[jl][1]);
            s.z = f2bf(acc[jl][2]); s.w = f2bf(acc[jl][3]);
            *(short4*)&vb[((size_t)ib * DV + c) * N_PIX + px_base] = s;
        }
    }
}

// ---------------------------------------------------------------------------
// K2: MFMA flash attention — one barrier per chunk (r17 structure, audited
// correct) with launch_bounds(256,3): grid 768 = 3 blocks/CU anyway, so the
// (256,4) VGPR cap was pure loss — r17's spills (FETCH+3.9MB, WRITE+13MB)
// came from the 64-reg tier, not the schedule. k_lds/p_lds double-buffered;
// region = [commit K(t+1) | issue K(t+2),V(t+1) | QK(t)] -> barrier -> PV(t).
// ---------------------------------------------------------------------------
__global__ __launch_bounds__(256, 3) void attn_kernel(
    const short* __restrict__ qg, const short* __restrict__ kg,
    const short* __restrict__ vg,
    float* __restrict__ out1, float* __restrict__ out2,
    short* __restrict__ featp, float* __restrict__ lpart)
{
    __shared__ short k_lds[2][64 * 24];   // dbuf [m][d], pitch 24 shorts
    __shared__ short p_lds[2][64 * 72];   // dbuf [n][m], pitch 72 shorts

    const int tid = threadIdx.x;
    const int lane = tid & 63;
    const int w = tid >> 6;
    const int gk = lane >> 4;
    const int l15 = lane & 15;

    const int B_ = blockIdx.x;
    const int pb = B_ & 3;
    const int mh = (B_ >> 2) % 3;
    const int nt = B_ / 12;
    const int n0 = nt * 64;
    const int br = pb >> 1, b = pb & 1;
    const int tstart = mh * 22;
    const int tend = (mh == 2) ? 64 : tstart + 22;   // 22/22/20, all even

    const short* qp = qg + (size_t)pb * N_PIX * 16;
    const short* kp = kg + (size_t)((br ^ 1) * 2 + b) * N_PIX * 16;
    const short* vp = vg + (size_t)pb * DV * N_PIX;

    bf16x8 aq = {};
    if (lane < 32)
        aq = *(const bf16x8*)&qp[(size_t)(n0 + w * 16 + l15) * 16 + gk * 8];

    f32x4 acc[2][4];
    #pragma unroll
    for (int cc = 0; cc < 2; ++cc)
        #pragma unroll
        for (int nb = 0; nb < 4; ++nb) acc[cc][nb] = (f32x4){0.f, 0.f, 0.f, 0.f};
    float lsum[4] = {0.f, 0.f, 0.f, 0.f};

    const short* vbase = vp + (size_t)(w * 32 + l15) * N_PIX + gk * 8;
    const int krow = tid - 192;

    int4 vbuf0[4], vbuf1[4];
    int4 kr0 = {}, kr1 = {};

    {   // prologue: V(tstart)->vbuf0; K(tstart)->k_lds[0]; K(tstart+1)->kr regs
        #pragma unroll
        for (int cc = 0; cc < 2; ++cc)
            #pragma unroll
            for (int m2 = 0; m2 < 2; ++m2)
                vbuf0[cc * 2 + m2] = *(const int4*)
                    &vbase[(size_t)cc * 16 * N_PIX + tstart * 64 + m2 * 32];
        if (tid >= 192) {
            int4 t0a = *(const int4*)&kp[(size_t)(tstart * 64 + krow) * 16];
            int4 t0b = *(const int4*)&kp[(size_t)(tstart * 64 + krow) * 16 + 8];
            *(int4*)&k_lds[0][krow * 24] = t0a;
            *(int4*)&k_lds[0][krow * 24 + 8] = t0b;
            if (tstart + 1 < tend) {
                kr0 = *(const int4*)&kp[(size_t)((tstart + 1) * 64 + krow) * 16];
                kr1 = *(const int4*)&kp[(size_t)((tstart + 1) * 64 + krow) * 16 + 8];
            }
        }
        __syncthreads();
    }

    for (int t0 = tstart; t0 < tend; t0 += 2) {
        #pragma unroll
        for (int half = 0; half < 2; ++half) {
            const int t = t0 + half;
            int4* vcur = half ? vbuf1 : vbuf0;
            int4* vnxt = half ? vbuf0 : vbuf1;
            // commit K(t+1) into the other k buffer (its last reader QK(t-1)
            // finished before the previous barrier)
            if (t + 1 < tend && tid >= 192) {
                *(int4*)&k_lds[half ^ 1][krow * 24] = kr0;
                *(int4*)&k_lds[half ^ 1][krow * 24 + 8] = kr1;
            }
            // issue K(t+2) and V(t+1); latency hides under QK + barrier + PV
            if (t + 2 < tend && tid >= 192) {
                kr0 = *(const int4*)&kp[(size_t)((t + 2) * 64 + krow) * 16];
                kr1 = *(const int4*)&kp[(size_t)((t + 2) * 64 + krow) * 16 + 8];
            }
            if (t + 1 < tend) {
                #pragma unroll
                for (int cc = 0; cc < 2; ++cc)
                    #pragma unroll
                    for (int m2 = 0; m2 < 2; ++m2)
                        vnxt[cc * 2 + m2] = *(const int4*)
                            &vbase[(size_t)cc * 16 * N_PIX + (t + 1) * 64 + m2 * 32];
            }
            // QK(t): k_lds[half] -> exp -> p_lds[half]
            #pragma unroll
            for (int h = 0; h < 4; ++h) {
                bf16x8 bk_ = {};
                if (lane < 32)
                    bk_ = *(const bf16x8*)&k_lds[half][(h * 16 + l15) * 24 + gk * 8];
                f32x4 s = __builtin_amdgcn_mfma_f32_16x16x32_bf16(
                    aq, bk_, (f32x4){0.f, 0.f, 0.f, 0.f}, 0, 0, 0);
                #pragma unroll
                for (int rr = 0; rr < 4; ++rr) {
                    float e = __expf(s[rr] * 0.25f);
                    lsum[rr] += e;
                    unsigned u = __builtin_bit_cast(unsigned, e);
                    p_lds[half][(w * 16 + gk * 4 + rr) * 72 + h * 16 + l15] = (short)(u >> 16);
                }
            }
            __syncthreads();   // the ONLY barrier per chunk
            // PV(t): p_lds[half] x V(regs)
            __builtin_amdgcn_s_setprio(1);
            #pragma unroll
            for (int m2 = 0; m2 < 2; ++m2) {
                #pragma unroll
                for (int nb = 0; nb < 4; ++nb) {
                    bf16x8 bp = *(const bf16x8*)
                        &p_lds[half][(nb * 16 + l15) * 72 + m2 * 32 + gk * 8];
                    #pragma unroll
                    for (int cc = 0; cc < 2; ++cc) {
                        bf16x8 av = __builtin_bit_cast(bf16x8, vcur[cc * 2 + m2]);
                        acc[cc][nb] = __builtin_amdgcn_mfma_f32_16x16x32_bf16(
                            av, bp, acc[cc][nb], 0, 0, 0);
                    }
                }
            }
            __builtin_amdgcn_s_setprio(0);
            // no trailing barrier: next chunk uses the other buffers
        }
    }

    #pragma unroll
    for (int rr = 0; rr < 4; ++rr) {
        float v = lsum[rr];
        v += __shfl_xor(v, 1); v += __shfl_xor(v, 2);
        v += __shfl_xor(v, 4); v += __shfl_xor(v, 8);
        lsum[rr] = v;
    }
    if (l15 == 0) {
        #pragma unroll
        for (int rr = 0; rr < 4; ++rr)
            lpart[(size_t)(pb * 3 + mh) * N_PIX + n0 + w * 16 + gk * 4 + rr] = lsum[rr];
    }

    if (mh == 0) {   // f32 partial at final location (c<128 of out1/out2)
        float* Od = (br ? out2 : out1) + (size_t)b * CCH * N_PIX;
        #pragma unroll
        for (int cc = 0; cc < 2; ++cc)
            #pragma unroll
            for (int nb = 0; nb < 4; ++nb)
                #pragma unroll
                for (int rr = 0; rr < 4; ++rr) {
                    int c = w * 32 + cc * 16 + gk * 4 + rr;
                    Od[(size_t)c * N_PIX + n0 + nb * 16 + l15] = acc[cc][nb][rr];
                }
    } else {
        // bf16 tiled slot via LDS repack (p_lds[0] region, [c][66])
        __syncthreads();
        short* pf = &p_lds[0][0];
        short* Ps = featp + (size_t)(pb * 2 + (mh - 1)) * (64 * 128 * 64)
                          + (size_t)nt * (128 * 64);
        #pragma unroll
        for (int chalf = 0; chalf < 2; ++chalf) {
            if ((w >> 1) == chalf) {   // waves 0,1 -> c 0..63; waves 2,3 -> 64..127
                int crel_base = (w & 1) * 32;
                #pragma unroll
                for (int cc = 0; cc < 2; ++cc)
                    #pragma unroll
                    for (int nb = 0; nb < 4; ++nb)
                        #pragma unroll
                        for (int rr = 0; rr < 4; ++rr) {
                            int crel = crel_base + cc * 16 + gk * 4 + rr;
                            pf[crel * 66 + nb * 16 + l15] = f2bf(acc[cc][nb][rr]);
                        }
            }
            __syncthreads();
            for (int idx = tid; idx < 512; idx += 256) {
                int cr = idx >> 3, seg = idx & 7;
                int4 v = *(const int4*)&pf[cr * 66 + seg * 8];
                *(int4*)&Ps[(size_t)(chalf * 64 + cr) * 64 + seg * 8] = v;
            }
            __syncthreads();
        }
    }
}

// ---------------------------------------------------------------------------
// K2b: merge 3 partials (1 f32 in-place + 2 bf16 tiles) + epilogue + prep_s.
// grid (128, 2): x = 32-px tile, y = b. block 256. (r11 exact)
// ---------------------------------------------------------------------------
__global__ __launch_bounds__(256) void merge_kernel(
    const float* __restrict__ x1, const float* __restrict__ x2,
    const short* __restrict__ featp, const float* __restrict__ lpart,
    const float* __restrict__ gamma_p,
    float* __restrict__ out1, float* __restrict__ out2,
    short* __restrict__ s_t)
{
    __shared__ short st[32 * 264];
    __shared__ float rls[2][32];
    const int tid = threadIdx.x;
    const int px0 = blockIdx.x * 32;
    const int b = blockIdx.y;
    const int nt = blockIdx.x >> 1;
    const int q32 = (blockIdx.x & 1) * 32;
    const float* xa_ = x1 + (size_t)b * CCH * N_PIX;
    const float* xb_ = x2 + (size_t)b * CCH * N_PIX;
    float* o1 = out1 + (size_t)b * CCH * N_PIX;   // holds pb=b   mh=0 f32 partial
    float* o2 = out2 + (size_t)b * CCH * N_PIX;   // holds pb=2+b mh=0 f32 partial
    const short* T10 = featp + (size_t)(b * 2 + 0) * (64 * 128 * 64) + (size_t)nt * (128 * 64);
    const short* T11 = featp + (size_t)(b * 2 + 1) * (64 * 128 * 64) + (size_t)nt * (128 * 64);
    const short* T20 = featp + (size_t)((2 + b) * 2 + 0) * (64 * 128 * 64) + (size_t)nt * (128 * 64);
    const short* T21 = featp + (size_t)((2 + b) * 2 + 1) * (64 * 128 * 64) + (size_t)nt * (128 * 64);

    if (tid < 64) {
        int h = tid >> 5, j = tid & 31;
        int pbh = h ? (2 + b) : b;
        float l = lpart[(size_t)(pbh * 3 + 0) * N_PIX + px0 + j]
                + lpart[(size_t)(pbh * 3 + 1) * N_PIX + px0 + j]
                + lpart[(size_t)(pbh * 3 + 2) * N_PIX + px0 + j];
        rls[h][j] = 1.0f / l;
    }
    __syncthreads();
    const float gmm = gamma_p[0];

    for (int idx = tid; idx < 2048; idx += 256) {
        int c = idx >> 3, p4 = idx & 7;
        size_t off = (size_t)c * N_PIX + px0 + p4 * 4;
        float4 va = *(const float4*)&xa_[off];
        float4 vb2 = *(const float4*)&xb_[off];
        float4 r1, r2;
        if (c < 128) {
            int toff = c * 64 + q32 + p4 * 4;
            float4 pa = *(const float4*)&o1[off];
            float4 pc = *(const float4*)&o2[off];
            float4 a1 = bf4_load(&T10[toff]);
            float4 a2 = bf4_load(&T11[toff]);
            float4 c1 = bf4_load(&T20[toff]);
            float4 c2 = bf4_load(&T21[toff]);
            r1.x = gmm * (pa.x + a1.x + a2.x) * rls[0][p4 * 4 + 0] + va.x;
            r1.y = gmm * (pa.y + a1.y + a2.y) * rls[0][p4 * 4 + 1] + va.y;
            r1.z = gmm * (pa.z + a1.z + a2.z) * rls[0][p4 * 4 + 2] + va.z;
            r1.w = gmm * (pa.w + a1.w + a2.w) * rls[0][p4 * 4 + 3] + va.w;
            r2.x = gmm * (pc.x + c1.x + c2.x) * rls[1][p4 * 4 + 0] + vb2.x;
            r2.y = gmm * (pc.y + c1.y + c2.y) * rls[1][p4 * 4 + 1] + vb2.y;
            r2.z = gmm * (pc.z + c1.z + c2.z) * rls[1][p4 * 4 + 2] + vb2.z;
            r2.w = gmm * (pc.w + c1.w + c2.w) * rls[1][p4 * 4 + 3] + vb2.w;
        } else {
            size_t offl = (size_t)(c - 128) * N_PIX + px0 + p4 * 4;
            float4 val = *(const float4*)&xa_[offl];
            float4 vbl = *(const float4*)&xb_[offl];
            r1.x = gmm * val.x + va.x; r1.y = gmm * val.y + va.y;
            r1.z = gmm * val.z + va.z; r1.w = gmm * val.w + va.w;
            r2.x = gmm * vbl.x + vb2.x; r2.y = gmm * vbl.y + vb2.y;
            r2.z = gmm * vbl.z + vb2.z; r2.w = gmm * vbl.w + vb2.w;
        }
        *(float4*)&o1[off] = r1;
        *(float4*)&o2[off] = r2;
        st[(p4 * 4 + 0) * 264 + c] = f2bf(r1.x + r2.x);
        st[(p4 * 4 + 1) * 264 + c] = f2bf(r1.y + r2.y);
        st[(p4 * 4 + 2) * 264 + c] = f2bf(r1.z + r2.z);
        st[(p4 * 4 + 3) * 264 + c] = f2bf(r1.w + r2.w);
    }
    __syncthreads();
    for (int idx = tid; idx < 1024; idx += 256) {
        int px = idx >> 5, seg = idx & 31;
        int4 v = *(const int4*)&st[px * 264 + seg * 8];
        *(int4*)&s_t[((size_t)b * N_PIX + px0 + px) * CCH + seg * 8] = v;
    }
}

// ---------------------------------------------------------------------------
// K3b: prep_w — blocks <288: Wcat -> bf16 A-fragment order.
//      blocks >=288 (40): pack Wq|Wk|Wv -> wqkv bf16 [160][256]. (r11 exact)
// ---------------------------------------------------------------------------
__global__ __launch_bounds__(256) void prep_w(
    const float* __restrict__ Wcat,
    const float* __restrict__ Wq, const float* __restrict__ Wk,
    const float* __restrict__ Wv,
    short* __restrict__ wfmt, short* __restrict__ wqkv)
{
    if (blockIdx.x < 288) {
        int idx = blockIdx.x * 256 + threadIdx.x;
        int lane = idx & 63;
        int ocg = (idx >> 6) & 15;
        int chunk = (idx >> 10) & 7;
        int tap = idx >> 13;
        int oc = ocg * 16 + (lane & 15);
        int ic0 = chunk * 32 + (lane >> 4) * 8;
        short8 v;
        #pragma unroll
        for (int j = 0; j < 8; ++j)
            v[j] = f2bf(Wcat[((size_t)oc * CCH + ic0 + j) * 9 + tap]);
        *(short8*)&wfmt[(size_t)idx * 8] = v;
    } else {
        int idx = (blockIdx.x - 288) * 1024 + threadIdx.x * 4;   // 0..40959
        int r = idx >> 8, c = idx & 255;
        const float* src;
        if (r < 16)      src = Wq + (size_t)r * CCH + c;
        else if (r < 32) src = Wk + (size_t)(r - 16) * CCH + c;
        else             src = Wv + (size_t)(r - 32) * CCH + c;
        float4 f = *(const float4*)src;
        short4 s;
        s.x = f2bf(f.x); s.y = f2bf(f.y); s.z = f2bf(f.z); s.w = f2bf(f.w);
        *(short4*)&wqkv[idx] = s;
    }
}

// ---------------------------------------------------------------------------
// K3c: conv implicit GEMM, oc-split 32/block, 4 blocks/CU (r17/r18 proven).
// grid 1024: oc_t = bx&7 (32 oc), pt = bx>>3: b = pt>>6, h0 = pt&63.
// ---------------------------------------------------------------------------
__global__ __launch_bounds__(256, 4) void conv_mfma(
    const short* __restrict__ s_t, const short* __restrict__ wfmt,
    const float* __restrict__ bn_gamma, const float* __restrict__ bn_beta,
    float* __restrict__ feat)
{
    __shared__ short s_lds[198 * 40];   // 3 rows x 66 wi, pitch 40
    const int tid = threadIdx.x;
    const int lane = tid & 63;
    const int wv = tid >> 6;
    const int g = lane >> 4, l15 = lane & 15;

    const int bx = blockIdx.x;
    const int oc_t = bx & 7;
    const int pt = bx >> 3;
    const int b = pt >> 6;
    const int h0 = pt & 63;

    f32x4 acc[2] = {};   // [ocg]

    const short* sbase = s_t + (size_t)b * N_PIX * CCH;
    const short* wf = wfmt + ((size_t)(oc_t * 2) * 64 + lane) * 8;

    for (int ci = 0; ci < 8; ++ci) {
        const int ic0 = ci * 32;
        __syncthreads();
        for (int idx = tid; idx < 792; idx += 256) {
            int seg = idx & 3, pos = idx >> 2;      // pos = row*66 + wi
            int row = pos / 66, wi = pos - row * 66;
            int hr = h0 - 1 + row, w = wi - 1;
            int4 val = {0, 0, 0, 0};
            if (hr >= 0 && hr < 64 && (unsigned)w < 64u)
                val = *(const int4*)&sbase[((size_t)(hr * 64 + w)) * CCH + ic0 + seg * 8];
            *(int4*)&s_lds[pos * 40 + seg * 8] = val;
        }
        __syncthreads();

        const short* wfc = wf + (size_t)ci * 8192;
        bf16x8 a0[2], a1[2];
        #pragma unroll
        for (int j = 0; j < 2; ++j) a0[j] = *(const bf16x8*)&wfc[j * 512];

        for (int tap = 0; tap < 9; ++tap) {
            bf16x8* ac = (tap & 1) ? a1 : a0;
            bf16x8* an = (tap & 1) ? a0 : a1;
            if (tap < 8) {
                const short* wfn = wfc + (size_t)(tap + 1) * 65536;
                #pragma unroll
                for (int j = 0; j < 2; ++j) an[j] = *(const bf16x8*)&wfn[j * 512];
            }
            int ky = (tap >= 6) ? 2 : (tap >= 3 ? 1 : 0);
            int kx = tap - ky * 3;
            bf16x8 bb = *(const bf16x8*)
                &s_lds[(ky * 66 + wv * 16 + l15 + kx) * 40 + g * 8];
            #pragma unroll
            for (int j = 0; j < 2; ++j)
                acc[j] = __builtin_amdgcn_mfma_f32_16x16x32_bf16(
                    ac[j], bb, acc[j], 0, 0, 0);
        }
    }

    const float inv = rsqrtf(1.0f + 1e-5f);
    const int wcol = wv * 16 + l15;
    #pragma unroll
    for (int j = 0; j < 2; ++j) {
        #pragma unroll
        for (int r = 0; r < 4; ++r) {
            int oc = oc_t * 32 + j * 16 + g * 4 + r;
            float y = acc[j][r] * (bn_gamma[oc] * inv) + bn_beta[oc];
            feat[((size_t)b * CCH + oc) * N_PIX + h0 * 64 + wcol] = fmaxf(y, 0.f);
        }
    }
}

// ---------------------------------------------------------------------------
extern "C" void kernel_launch(void* const* d_in, const int* in_sizes, int n_in,
                              void* d_out, int out_size, void* d_ws, size_t ws_size,
                              hipStream_t stream) {
    const float* x1    = (const float*)d_in[0];
    const float* x2    = (const float*)d_in[1];
    const float* Wq    = (const float*)d_in[2];
    const float* bq    = (const float*)d_in[3];
    const float* Wk    = (const float*)d_in[4];
    const float* bk    = (const float*)d_in[5];
    const float* Wv    = (const float*)d_in[6];
    const float* bv    = (const float*)d_in[7];
    const float* gamma = (const float*)d_in[8];
    const float* Wcat  = (const float*)d_in[9];
    const float* bng   = (const float*)d_in[10];
    const float* bnb   = (const float*)d_in[11];

    float* out  = (float*)d_out;
    float* feat = out;                    // hosts 8 bf16 tiled partial slots pre-conv
    float* out1 = out + 2097152;
    float* out2 = out + 4194304;

    short* ws   = (short*)d_ws;
    short* qb   = ws;                     // 262144 shorts
    short* kb   = ws + 262144;            // 262144
    short* vb   = ws + 524288;            // 2097152
    short* s_t  = ws + 2621440;           // 2097152
    short* wfmt = ws + 4718592;           // 589824
    float* lp   = (float*)(ws + 5308416); // 12*4096 f32 l-partials
    short* wqkv = s_t;                    // aliases s_t (dead until merge writes it)

    prep_w<<<328, 256, 0, stream>>>(Wcat, Wq, Wk, Wv, wfmt, wqkv);
    qkv_kernel<<<dim3(64, 4), 512, 0, stream>>>(x1, x2, wqkv, bq, bk, bv, qb, kb, vb);
    attn_kernel<<<768, 256, 0, stream>>>(qb, kb, vb, out1, out2, (short*)feat, lp);
    merge_kernel<<<dim3(128, 2), 256, 0, stream>>>(x1, x2, (const short*)feat, lp, gamma, out1, out2, s_t);
    conv_mfma<<<1024, 256, 0, stream>>>(s_t, wfmt, bng, bnb, feat);
}

// Round 20
// 100.826 us; speedup vs baseline: 1.2773x; 1.0090x over previous
//
#include <hip/hip_runtime.h>

#define N_PIX 4096
#define CCH 256
#define DV 128

typedef __attribute__((ext_vector_type(8))) short bf16x8;
typedef __attribute__((ext_vector_type(4))) short bf16x4;
typedef __attribute__((ext_vector_type(4))) float f32x4;
typedef __attribute__((ext_vector_type(8))) short short8;

#if defined(__has_builtin)
#  if __has_builtin(__builtin_amdgcn_mfma_f32_16x16x16bf16_1k)
#    define HAS_MFMA16 1
#  endif
#endif
#ifndef HAS_MFMA16
#  define HAS_MFMA16 0
#endif

__device__ __forceinline__ short f2bf(float f) {
    unsigned u = __builtin_bit_cast(unsigned, f);
    u += 0x7fffu + ((u >> 16) & 1u);
    return (short)(u >> 16);
}

__device__ __forceinline__ float4 bf4_load(const short* p) {
    short4 s = *(const short4*)p;
    float4 f;
    f.x = __builtin_bit_cast(float, (unsigned)((unsigned short)s.x) << 16);
    f.y = __builtin_bit_cast(float, (unsigned)((unsigned short)s.y) << 16);
    f.z = __builtin_bit_cast(float, (unsigned)((unsigned short)s.z) << 16);
    f.w = __builtin_bit_cast(float, (unsigned)((unsigned short)s.w) << 16);
    return f;
}

// ---------------------------------------------------------------------------
// K1: fused 1x1 convs as ONE bf16 MFMA GEMM (r11 exact).
// ---------------------------------------------------------------------------
__global__ __launch_bounds__(512) void qkv_kernel(
    const float* __restrict__ x1, const float* __restrict__ x2,
    const short* __restrict__ wqkv,
    const float* __restrict__ bq, const float* __restrict__ bk,
    const float* __restrict__ bv,
    short* __restrict__ qb, short* __restrict__ kb, short* __restrict__ vb)
{
    __shared__ short xT[64][68];   // [px][c-chunk], pitch 68 shorts

    const int tid = threadIdx.x;
    const int lane = tid & 63;
    const int w = tid >> 6;
    const int g = lane >> 4, l15 = lane & 15;
    const int n0 = blockIdx.x * 64;
    const int ib = blockIdx.y;
    const int i = ib >> 1, b = ib & 1;
    const float* x = (i == 0 ? x1 : x2) + (size_t)b * CCH * N_PIX;

    const int px2 = tid & 31, c4 = tid >> 5;
    const int rhalf = (w >> 2) * 80;

    f32x4 acc[5];
    #pragma unroll
    for (int jl = 0; jl < 5; ++jl) {
        int rbase = rhalf + jl * 16;
        float bias;
        if (rbase == 0)       bias = bq[l15];
        else if (rbase == 16) bias = bk[l15];
        else                  bias = bv[rbase - 32 + l15];
        acc[jl] = (f32x4){bias, bias, bias, bias};
    }

    float2 xr[4];
    {
        #pragma unroll
        for (int jj = 0; jj < 4; ++jj)
            xr[jj] = *(const float2*)&x[(size_t)(c4 * 4 + jj) * N_PIX + n0 + px2 * 2];
    }

    for (int ci = 0; ci < 4; ++ci) {   // 4 chunks x 64 c = K 256
        __syncthreads();
        {
            short4 w0, w1;
            w0.x = f2bf(xr[0].x); w0.y = f2bf(xr[1].x); w0.z = f2bf(xr[2].x); w0.w = f2bf(xr[3].x);
            w1.x = f2bf(xr[0].y); w1.y = f2bf(xr[1].y); w1.z = f2bf(xr[2].y); w1.w = f2bf(xr[3].y);
            *(short4*)&xT[px2 * 2 + 0][c4 * 4] = w0;
            *(short4*)&xT[px2 * 2 + 1][c4 * 4] = w1;
        }
        __syncthreads();
        if (ci < 3) {
            #pragma unroll
            for (int jj = 0; jj < 4; ++jj)
                xr[jj] = *(const float2*)
                    &x[(size_t)((ci + 1) * 64 + c4 * 4 + jj) * N_PIX + n0 + px2 * 2];
        }
        bf16x8 a0 = *(const bf16x8*)&xT[(w & 3) * 16 + l15][g * 8];
        bf16x8 a1 = *(const bf16x8*)&xT[(w & 3) * 16 + l15][32 + g * 8];
        #pragma unroll
        for (int jl = 0; jl < 5; ++jl) {
            int rbase = rhalf + jl * 16;
            const short* wrow = wqkv + (size_t)(rbase + l15) * CCH + ci * 64;
            bf16x8 b0 = *(const bf16x8*)&wrow[g * 8];
            bf16x8 b1 = *(const bf16x8*)&wrow[32 + g * 8];
            acc[jl] = __builtin_amdgcn_mfma_f32_16x16x32_bf16(a0, b0, acc[jl], 0, 0, 0);
            acc[jl] = __builtin_amdgcn_mfma_f32_16x16x32_bf16(a1, b1, acc[jl], 0, 0, 0);
        }
    }

    const int px_base = n0 + (w & 3) * 16 + g * 4;
    #pragma unroll
    for (int jl = 0; jl < 5; ++jl) {
        int rbase = rhalf + jl * 16;
        if (rbase == 0) {
            #pragma unroll
            for (int rr = 0; rr < 4; ++rr)
                qb[((size_t)ib * N_PIX + px_base + rr) * 16 + l15] = f2bf(acc[jl][rr]);
        } else if (rbase == 16) {
            #pragma unroll
            for (int rr = 0; rr < 4; ++rr)
                kb[((size_t)ib * N_PIX + px_base + rr) * 16 + l15] = f2bf(acc[jl][rr]);
        } else {
            int c = rbase - 32 + l15;
            short4 s;
            s.x = f2bf(acc[jl][0]); s.y = f2bf(acc[jl][1]);
            s.z = f2bf(acc[jl][2]); s.w = f2bf(acc[jl][3]);
            *(short4*)&vb[((size_t)ib * DV + c) * N_PIX + px_base] = s;
        }
    }
}

// ---------------------------------------------------------------------------
// K2: MFMA flash attention — r19 one-barrier structure (equal-best, no
// spill at launch_bounds(256,3)) with QK on mfma_f32_16x16x16_bf16 when
// available: K=16 fits D exactly (no zero half, all 64 lanes carry data,
// k_lds reads b128 -> b64). Guarded by __has_builtin; fallback = r19 exact.
// D mapping identical (col=m=l15, row=n=gk*4+rr) so P-store is unchanged.
// ---------------------------------------------------------------------------
__global__ __launch_bounds__(256, 3) void attn_kernel(
    const short* __restrict__ qg, const short* __restrict__ kg,
    const short* __restrict__ vg,
    float* __restrict__ out1, float* __restrict__ out2,
    short* __restrict__ featp, float* __restrict__ lpart)
{
    __shared__ short k_lds[2][64 * 24];   // dbuf [m][d], pitch 24 shorts
    __shared__ short p_lds[2][64 * 72];   // dbuf [n][m], pitch 72 shorts

    const int tid = threadIdx.x;
    const int lane = tid & 63;
    const int w = tid >> 6;
    const int gk = lane >> 4;
    const int l15 = lane & 15;

    const int B_ = blockIdx.x;
    const int pb = B_ & 3;
    const int mh = (B_ >> 2) % 3;
    const int nt = B_ / 12;
    const int n0 = nt * 64;
    const int br = pb >> 1, b = pb & 1;
    const int tstart = mh * 22;
    const int tend = (mh == 2) ? 64 : tstart + 22;   // 22/22/20, all even

    const short* qp = qg + (size_t)pb * N_PIX * 16;
    const short* kp = kg + (size_t)((br ^ 1) * 2 + b) * N_PIX * 16;
    const short* vp = vg + (size_t)pb * DV * N_PIX;

#if HAS_MFMA16
    // all 64 lanes: row n = l15(+w*16), k = d = gk*4..gk*4+3
    bf16x4 aq16 = *(const bf16x4*)&qp[(size_t)(n0 + w * 16 + l15) * 16 + gk * 4];
#else
    bf16x8 aq = {};
    if (lane < 32)
        aq = *(const bf16x8*)&qp[(size_t)(n0 + w * 16 + l15) * 16 + gk * 8];
#endif

    f32x4 acc[2][4];
    #pragma unroll
    for (int cc = 0; cc < 2; ++cc)
        #pragma unroll
        for (int nb = 0; nb < 4; ++nb) acc[cc][nb] = (f32x4){0.f, 0.f, 0.f, 0.f};
    float lsum[4] = {0.f, 0.f, 0.f, 0.f};

    const short* vbase = vp + (size_t)(w * 32 + l15) * N_PIX + gk * 8;
    const int krow = tid - 192;

    int4 vbuf0[4], vbuf1[4];
    int4 kr0 = {}, kr1 = {};

    {   // prologue: V(tstart)->vbuf0; K(tstart)->k_lds[0]; K(tstart+1)->kr regs
        #pragma unroll
        for (int cc = 0; cc < 2; ++cc)
            #pragma unroll
            for (int m2 = 0; m2 < 2; ++m2)
                vbuf0[cc * 2 + m2] = *(const int4*)
                    &vbase[(size_t)cc * 16 * N_PIX + tstart * 64 + m2 * 32];
        if (tid >= 192) {
            int4 t0a = *(const int4*)&kp[(size_t)(tstart * 64 + krow) * 16];
            int4 t0b = *(const int4*)&kp[(size_t)(tstart * 64 + krow) * 16 + 8];
            *(int4*)&k_lds[0][krow * 24] = t0a;
            *(int4*)&k_lds[0][krow * 24 + 8] = t0b;
            if (tstart + 1 < tend) {
                kr0 = *(const int4*)&kp[(size_t)((tstart + 1) * 64 + krow) * 16];
                kr1 = *(const int4*)&kp[(size_t)((tstart + 1) * 64 + krow) * 16 + 8];
            }
        }
        __syncthreads();
    }

    for (int t0 = tstart; t0 < tend; t0 += 2) {
        #pragma unroll
        for (int half = 0; half < 2; ++half) {
            const int t = t0 + half;
            int4* vcur = half ? vbuf1 : vbuf0;
            int4* vnxt = half ? vbuf0 : vbuf1;
            // commit K(t+1) into the other k buffer (its last reader QK(t-1)
            // finished before the previous barrier)
            if (t + 1 < tend && tid >= 192) {
                *(int4*)&k_lds[half ^ 1][krow * 24] = kr0;
                *(int4*)&k_lds[half ^ 1][krow * 24 + 8] = kr1;
            }
            // issue K(t+2) and V(t+1); latency hides under QK + barrier + PV
            if (t + 2 < tend && tid >= 192) {
                kr0 = *(const int4*)&kp[(size_t)((t + 2) * 64 + krow) * 16];
                kr1 = *(const int4*)&kp[(size_t)((t + 2) * 64 + krow) * 16 + 8];
            }
            if (t + 1 < tend) {
                #pragma unroll
                for (int cc = 0; cc < 2; ++cc)
                    #pragma unroll
                    for (int m2 = 0; m2 < 2; ++m2)
                        vnxt[cc * 2 + m2] = *(const int4*)
                            &vbase[(size_t)cc * 16 * N_PIX + (t + 1) * 64 + m2 * 32];
            }
            // QK(t): k_lds[half] -> exp -> p_lds[half]
            #pragma unroll
            for (int h = 0; h < 4; ++h) {
#if HAS_MFMA16
                bf16x4 bk16 = *(const bf16x4*)&k_lds[half][(h * 16 + l15) * 24 + gk * 4];
                f32x4 s = __builtin_amdgcn_mfma_f32_16x16x16bf16_1k(
                    aq16, bk16, (f32x4){0.f, 0.f, 0.f, 0.f}, 0, 0, 0);
#else
                bf16x8 bk_ = {};
                if (lane < 32)
                    bk_ = *(const bf16x8*)&k_lds[half][(h * 16 + l15) * 24 + gk * 8];
                f32x4 s = __builtin_amdgcn_mfma_f32_16x16x32_bf16(
                    aq, bk_, (f32x4){0.f, 0.f, 0.f, 0.f}, 0, 0, 0);
#endif
                #pragma unroll
                for (int rr = 0; rr < 4; ++rr) {
                    float e = __expf(s[rr] * 0.25f);
                    lsum[rr] += e;
                    unsigned u = __builtin_bit_cast(unsigned, e);
                    p_lds[half][(w * 16 + gk * 4 + rr) * 72 + h * 16 + l15] = (short)(u >> 16);
                }
            }
            __syncthreads();   // the ONLY barrier per chunk
            // PV(t): p_lds[half] x V(regs)
            __builtin_amdgcn_s_setprio(1);
            #pragma unroll
            for (int m2 = 0; m2 < 2; ++m2) {
                #pragma unroll
                for (int nb = 0; nb < 4; ++nb) {
                    bf16x8 bp = *(const bf16x8*)
                        &p_lds[half][(nb * 16 + l15) * 72 + m2 * 32 + gk * 8];
                    #pragma unroll
                    for (int cc = 0; cc < 2; ++cc) {
                        bf16x8 av = __builtin_bit_cast(bf16x8, vcur[cc * 2 + m2]);
                        acc[cc][nb] = __builtin_amdgcn_mfma_f32_16x16x32_bf16(
                            av, bp, acc[cc][nb], 0, 0, 0);
                    }
                }
            }
            __builtin_amdgcn_s_setprio(0);
            // no trailing barrier: next chunk uses the other buffers
        }
    }

    #pragma unroll
    for (int rr = 0; rr < 4; ++rr) {
        float v = lsum[rr];
        v += __shfl_xor(v, 1); v += __shfl_xor(v, 2);
        v += __shfl_xor(v, 4); v += __shfl_xor(v, 8);
        lsum[rr] = v;
    }
    if (l15 == 0) {
        #pragma unroll
        for (int rr = 0; rr < 4; ++rr)
            lpart[(size_t)(pb * 3 + mh) * N_PIX + n0 + w * 16 + gk * 4 + rr] = lsum[rr];
    }

    if (mh == 0) {   // f32 partial at final location (c<128 of out1/out2)
        float* Od = (br ? out2 : out1) + (size_t)b * CCH * N_PIX;
        #pragma unroll
        for (int cc = 0; cc < 2; ++cc)
            #pragma unroll
            for (int nb = 0; nb < 4; ++nb)
                #pragma unroll
                for (int rr = 0; rr < 4; ++rr) {
                    int c = w * 32 + cc * 16 + gk * 4 + rr;
                    Od[(size_t)c * N_PIX + n0 + nb * 16 + l15] = acc[cc][nb][rr];
                }
    } else {
        // bf16 tiled slot via LDS repack (p_lds[0] region, [c][66])
        __syncthreads();
        short* pf = &p_lds[0][0];
        short* Ps = featp + (size_t)(pb * 2 + (mh - 1)) * (64 * 128 * 64)
                          + (size_t)nt * (128 * 64);
        #pragma unroll
        for (int chalf = 0; chalf < 2; ++chalf) {
            if ((w >> 1) == chalf) {   // waves 0,1 -> c 0..63; waves 2,3 -> 64..127
                int crel_base = (w & 1) * 32;
                #pragma unroll
                for (int cc = 0; cc < 2; ++cc)
                    #pragma unroll
                    for (int nb = 0; nb < 4; ++nb)
                        #pragma unroll
                        for (int rr = 0; rr < 4; ++rr) {
                            int crel = crel_base + cc * 16 + gk * 4 + rr;
                            pf[crel * 66 + nb * 16 + l15] = f2bf(acc[cc][nb][rr]);
                        }
            }
            __syncthreads();
            for (int idx = tid; idx < 512; idx += 256) {
                int cr = idx >> 3, seg = idx & 7;
                int4 v = *(const int4*)&pf[cr * 66 + seg * 8];
                *(int4*)&Ps[(size_t)(chalf * 64 + cr) * 64 + seg * 8] = v;
            }
            __syncthreads();
        }
    }
}

// ---------------------------------------------------------------------------
// K2b: merge 3 partials (1 f32 in-place + 2 bf16 tiles) + epilogue + prep_s.
// grid (128, 2): x = 32-px tile, y = b. block 256. (r11 exact)
// ---------------------------------------------------------------------------
__global__ __launch_bounds__(256) void merge_kernel(
    const float* __restrict__ x1, const float* __restrict__ x2,
    const short* __restrict__ featp, const float* __restrict__ lpart,
    const float* __restrict__ gamma_p,
    float* __restrict__ out1, float* __restrict__ out2,
    short* __restrict__ s_t)
{
    __shared__ short st[32 * 264];
    __shared__ float rls[2][32];
    const int tid = threadIdx.x;
    const int px0 = blockIdx.x * 32;
    const int b = blockIdx.y;
    const int nt = blockIdx.x >> 1;
    const int q32 = (blockIdx.x & 1) * 32;
    const float* xa_ = x1 + (size_t)b * CCH * N_PIX;
    const float* xb_ = x2 + (size_t)b * CCH * N_PIX;
    float* o1 = out1 + (size_t)b * CCH * N_PIX;   // holds pb=b   mh=0 f32 partial
    float* o2 = out2 + (size_t)b * CCH * N_PIX;   // holds pb=2+b mh=0 f32 partial
    const short* T10 = featp + (size_t)(b * 2 + 0) * (64 * 128 * 64) + (size_t)nt * (128 * 64);
    const short* T11 = featp + (size_t)(b * 2 + 1) * (64 * 128 * 64) + (size_t)nt * (128 * 64);
    const short* T20 = featp + (size_t)((2 + b) * 2 + 0) * (64 * 128 * 64) + (size_t)nt * (128 * 64);
    const short* T21 = featp + (size_t)((2 + b) * 2 + 1) * (64 * 128 * 64) + (size_t)nt * (128 * 64);

    if (tid < 64) {
        int h = tid >> 5, j = tid & 31;
        int pbh = h ? (2 + b) : b;
        float l = lpart[(size_t)(pbh * 3 + 0) * N_PIX + px0 + j]
                + lpart[(size_t)(pbh * 3 + 1) * N_PIX + px0 + j]
                + lpart[(size_t)(pbh * 3 + 2) * N_PIX + px0 + j];
        rls[h][j] = 1.0f / l;
    }
    __syncthreads();
    const float gmm = gamma_p[0];

    for (int idx = tid; idx < 2048; idx += 256) {
        int c = idx >> 3, p4 = idx & 7;
        size_t off = (size_t)c * N_PIX + px0 + p4 * 4;
        float4 va = *(const float4*)&xa_[off];
        float4 vb2 = *(const float4*)&xb_[off];
        float4 r1, r2;
        if (c < 128) {
            int toff = c * 64 + q32 + p4 * 4;
            float4 pa = *(const float4*)&o1[off];
            float4 pc = *(const float4*)&o2[off];
            float4 a1 = bf4_load(&T10[toff]);
            float4 a2 = bf4_load(&T11[toff]);
            float4 c1 = bf4_load(&T20[toff]);
            float4 c2 = bf4_load(&T21[toff]);
            r1.x = gmm * (pa.x + a1.x + a2.x) * rls[0][p4 * 4 + 0] + va.x;
            r1.y = gmm * (pa.y + a1.y + a2.y) * rls[0][p4 * 4 + 1] + va.y;
            r1.z = gmm * (pa.z + a1.z + a2.z) * rls[0][p4 * 4 + 2] + va.z;
            r1.w = gmm * (pa.w + a1.w + a2.w) * rls[0][p4 * 4 + 3] + va.w;
            r2.x = gmm * (pc.x + c1.x + c2.x) * rls[1][p4 * 4 + 0] + vb2.x;
            r2.y = gmm * (pc.y + c1.y + c2.y) * rls[1][p4 * 4 + 1] + vb2.y;
            r2.z = gmm * (pc.z + c1.z + c2.z) * rls[1][p4 * 4 + 2] + vb2.z;
            r2.w = gmm * (pc.w + c1.w + c2.w) * rls[1][p4 * 4 + 3] + vb2.w;
        } else {
            size_t offl = (size_t)(c - 128) * N_PIX + px0 + p4 * 4;
            float4 val = *(const float4*)&xa_[offl];
            float4 vbl = *(const float4*)&xb_[offl];
            r1.x = gmm * val.x + va.x; r1.y = gmm * val.y + va.y;
            r1.z = gmm * val.z + va.z; r1.w = gmm * val.w + va.w;
            r2.x = gmm * vbl.x + vb2.x; r2.y = gmm * vbl.y + vb2.y;
            r2.z = gmm * vbl.z + vb2.z; r2.w = gmm * vbl.w + vb2.w;
        }
        *(float4*)&o1[off] = r1;
        *(float4*)&o2[off] = r2;
        st[(p4 * 4 + 0) * 264 + c] = f2bf(r1.x + r2.x);
        st[(p4 * 4 + 1) * 264 + c] = f2bf(r1.y + r2.y);
        st[(p4 * 4 + 2) * 264 + c] = f2bf(r1.z + r2.z);
        st[(p4 * 4 + 3) * 264 + c] = f2bf(r1.w + r2.w);
    }
    __syncthreads();
    for (int idx = tid; idx < 1024; idx += 256) {
        int px = idx >> 5, seg = idx & 31;
        int4 v = *(const int4*)&st[px * 264 + seg * 8];
        *(int4*)&s_t[((size_t)b * N_PIX + px0 + px) * CCH + seg * 8] = v;
    }
}

// ---------------------------------------------------------------------------
// K3b: prep_w — blocks <288: Wcat -> bf16 A-fragment order.
//      blocks >=288 (40): pack Wq|Wk|Wv -> wqkv bf16 [160][256]. (r11 exact)
// ---------------------------------------------------------------------------
__global__ __launch_bounds__(256) void prep_w(
    const float* __restrict__ Wcat,
    const float* __restrict__ Wq, const float* __restrict__ Wk,
    const float* __restrict__ Wv,
    short* __restrict__ wfmt, short* __restrict__ wqkv)
{
    if (blockIdx.x < 288) {
        int idx = blockIdx.x * 256 + threadIdx.x;
        int lane = idx & 63;
        int ocg = (idx >> 6) & 15;
        int chunk = (idx >> 10) & 7;
        int tap = idx >> 13;
        int oc = ocg * 16 + (lane & 15);
        int ic0 = chunk * 32 + (lane >> 4) * 8;
        short8 v;
        #pragma unroll
        for (int j = 0; j < 8; ++j)
            v[j] = f2bf(Wcat[((size_t)oc * CCH + ic0 + j) * 9 + tap]);
        *(short8*)&wfmt[(size_t)idx * 8] = v;
    } else {
        int idx = (blockIdx.x - 288) * 1024 + threadIdx.x * 4;   // 0..40959
        int r = idx >> 8, c = idx & 255;
        const float* src;
        if (r < 16)      src = Wq + (size_t)r * CCH + c;
        else if (r < 32) src = Wk + (size_t)(r - 16) * CCH + c;
        else             src = Wv + (size_t)(r - 32) * CCH + c;
        float4 f = *(const float4*)src;
        short4 s;
        s.x = f2bf(f.x); s.y = f2bf(f.y); s.z = f2bf(f.z); s.w = f2bf(f.w);
        *(short4*)&wqkv[idx] = s;
    }
}

// ---------------------------------------------------------------------------
// K3c: conv implicit GEMM, oc-split 32/block, 4 blocks/CU (r17/r18 proven).
// grid 1024: oc_t = bx&7 (32 oc), pt = bx>>3: b = pt>>6, h0 = pt&63.
// ---------------------------------------------------------------------------
__global__ __launch_bounds__(256, 4) void conv_mfma(
    const short* __restrict__ s_t, const short* __restrict__ wfmt,
    const float* __restrict__ bn_gamma, const float* __restrict__ bn_beta,
    float* __restrict__ feat)
{
    __shared__ short s_lds[198 * 40];   // 3 rows x 66 wi, pitch 40
    const int tid = threadIdx.x;
    const int lane = tid & 63;
    const int wv = tid >> 6;
    const int g = lane >> 4, l15 = lane & 15;

    const int bx = blockIdx.x;
    const int oc_t = bx & 7;
    const int pt = bx >> 3;
    const int b = pt >> 6;
    const int h0 = pt & 63;

    f32x4 acc[2] = {};   // [ocg]

    const short* sbase = s_t + (size_t)b * N_PIX * CCH;
    const short* wf = wfmt + ((size_t)(oc_t * 2) * 64 + lane) * 8;

    for (int ci = 0; ci < 8; ++ci) {
        const int ic0 = ci * 32;
        __syncthreads();
        for (int idx = tid; idx < 792; idx += 256) {
            int seg = idx & 3, pos = idx >> 2;      // pos = row*66 + wi
            int row = pos / 66, wi = pos - row * 66;
            int hr = h0 - 1 + row, w = wi - 1;
            int4 val = {0, 0, 0, 0};
            if (hr >= 0 && hr < 64 && (unsigned)w < 64u)
                val = *(const int4*)&sbase[((size_t)(hr * 64 + w)) * CCH + ic0 + seg * 8];
            *(int4*)&s_lds[pos * 40 + seg * 8] = val;
        }
        __syncthreads();

        const short* wfc = wf + (size_t)ci * 8192;
        bf16x8 a0[2], a1[2];
        #pragma unroll
        for (int j = 0; j < 2; ++j) a0[j] = *(const bf16x8*)&wfc[j * 512];

        for (int tap = 0; tap < 9; ++tap) {
            bf16x8* ac = (tap & 1) ? a1 : a0;
            bf16x8* an = (tap & 1) ? a0 : a1;
            if (tap < 8) {
                const short* wfn = wfc + (size_t)(tap + 1) * 65536;
                #pragma unroll
                for (int j = 0; j < 2; ++j) an[j] = *(const bf16x8*)&wfn[j * 512];
            }
            int ky = (tap >= 6) ? 2 : (tap >= 3 ? 1 : 0);
            int kx = tap - ky * 3;
            bf16x8 bb = *(const bf16x8*)
                &s_lds[(ky * 66 + wv * 16 + l15 + kx) * 40 + g * 8];
            #pragma unroll
            for (int j = 0; j < 2; ++j)
                acc[j] = __builtin_amdgcn_mfma_f32_16x16x32_bf16(
                    ac[j], bb, acc[j], 0, 0, 0);
        }
    }

    const float inv = rsqrtf(1.0f + 1e-5f);
    const int wcol = wv * 16 + l15;
    #pragma unroll
    for (int j = 0; j < 2; ++j) {
        #pragma unroll
        for (int r = 0; r < 4; ++r) {
            int oc = oc_t * 32 + j * 16 + g * 4 + r;
            float y = acc[j][r] * (bn_gamma[oc] * inv) + bn_beta[oc];
            feat[((size_t)b * CCH + oc) * N_PIX + h0 * 64 + wcol] = fmaxf(y, 0.f);
        }
    }
}

// ---------------------------------------------------------------------------
extern "C" void kernel_launch(void* const* d_in, const int* in_sizes, int n_in,
                              void* d_out, int out_size, void* d_ws, size_t ws_size,
                              hipStream_t stream) {
    const float* x1    = (const float*)d_in[0];
    const float* x2    = (const float*)d_in[1];
    const float* Wq    = (const float*)d_in[2];
    const float* bq    = (const float*)d_in[3];
    const float* Wk    = (const float*)d_in[4];
    const float* bk    = (const float*)d_in[5];
    const float* Wv    = (const float*)d_in[6];
    const float* bv    = (const float*)d_in[7];
    const float* gamma = (const float*)d_in[8];
    const float* Wcat  = (const float*)d_in[9];
    const float* bng   = (const float*)d_in[10];
    const float* bnb   = (const float*)d_in[11];

    float* out  = (float*)d_out;
    float* feat = out;                    // hosts 8 bf16 tiled partial slots pre-conv
    float* out1 = out + 2097152;
    float* out2 = out + 4194304;

    short* ws   = (short*)d_ws;
    short* qb   = ws;                     // 262144 shorts
    short* kb   = ws + 262144;            // 262144
    short* vb   = ws + 524288;            // 2097152
    short* s_t  = ws + 2621440;           // 2097152
    short* wfmt = ws + 4718592;           // 589824
    float* lp   = (float*)(ws + 5308416); // 12*4096 f32 l-partials
    short* wqkv = s_t;                    // aliases s_t (dead until merge writes it)

    prep_w<<<328, 256, 0, stream>>>(Wcat, Wq, Wk, Wv, wfmt, wqkv);
    qkv_kernel<<<dim3(64, 4), 512, 0, stream>>>(x1, x2, wqkv, bq, bk, bv, qb, kb, vb);
    attn_kernel<<<768, 256, 0, stream>>>(qb, kb, vb, out1, out2, (short*)feat, lp);
    merge_kernel<<<dim3(128, 2), 256, 0, stream>>>(x1, x2, (const short*)feat, lp, gamma, out1, out2, s_t);
    conv_mfma<<<1024, 256, 0, stream>>>(s_t, wfmt, bng, bnb, feat);
}